// Round 3
// baseline (20752.963 us; speedup 1.0000x reference)
//
#include <hip/hip_runtime.h>
#include <hip/hip_bf16.h>

// RecognitionODEGRU R2 — single persistent kernel, ~401 grid barriers instead of
// ~390 kernel launches. K-loop uses raw s_barrier + manual s_waitcnt vmcnt(12)
// so global_load_lds prefetch stays in flight across barriers (the drain at
// __syncthreads was R1's hidden serializer at 1 wave/SIMD).
//
// Shapes: B=512, T=8, D=512, H=512, LAT=64, NSTEPS=4.
// d_out: outs[-1] (512,128) | h (512,512) | c=zeros (512,512), f32.

#define B_ 512
#define T_ 8
#define D_ 512
#define H_ 512
#define NSTEPS_ 4
#define NB 256   // persistent grid: one block per CU
#define NT 256   // 4 waves

typedef short short8 __attribute__((ext_vector_type(8)));
typedef float f32x4 __attribute__((ext_vector_type(4)));
typedef __hip_bfloat16 bf16;

#define MODE_SWISH1 0  // z1 = swish(acc + b1 + tcur[row]*w1t[col]) -> bf16
#define MODE_SWISH  1  // z2 = swish(acc + bias) -> bf16
#define MODE_F32    2  // out = acc + bias -> f32
#define MODE_RK4    3  // k_e = acc + bias; fused RK4 state update

__device__ __forceinline__ float sigm(float x){ return 1.f/(1.f+__expf(-x)); }

__device__ __forceinline__ void async_cp16(const bf16* g, bf16* l){
  __builtin_amdgcn_global_load_lds((const __attribute__((address_space(1))) void*)g,
                                   (__attribute__((address_space(3))) void*)l, 16, 0, 0);
}
// vmcnt(N) only: expcnt=0x7, lgkmcnt=0xF (no wait), vmcnt hi bits 0 (N<=15).
#define WAITVM(N) __builtin_amdgcn_s_waitcnt(0xF70 | (N))

// Device-scope sense-free barrier: monotone counter, per-block arrival.
__device__ __forceinline__ void grid_bar(unsigned* cnt, unsigned target){
  __threadfence();                 // release: publish this block's writes
  __syncthreads();
  if (threadIdx.x == 0){
    __hip_atomic_fetch_add(cnt, 1u, __ATOMIC_RELAXED, __HIP_MEMORY_SCOPE_AGENT);
    while (__hip_atomic_load(cnt, __ATOMIC_RELAXED, __HIP_MEMORY_SCOPE_AGENT) < target)
      __builtin_amdgcn_s_sleep(4);
  }
  __syncthreads();
  __threadfence();                 // acquire: invalidate L1, see other blocks' writes
}

// One GEMM phase: C = act(A @ W^T + bias), tiles 32x64 grid-strided over NB blocks.
// BK=256 chunks, double-buffered via raw s_barrier + vmcnt(12) (12 loads/thread/chunk).
// LDS 16B-granule XOR swizzle (2-way bank aliasing = free; global_load_lds-compatible).
template<int MODE>
__device__ void run_gemm(int M, int N, int K,
    const bf16* __restrict__ A, int lda,
    const bf16* __restrict__ W, int ldw,
    const float* __restrict__ bias,
    float* __restrict__ outf, bf16* __restrict__ outb, int ldo,
    float* __restrict__ hbuf, float* __restrict__ kaccb, bf16* __restrict__ wbuf,
    const float* __restrict__ dtbuf, const float* __restrict__ t0buf,
    float* __restrict__ tcur, const float* __restrict__ w1t,
    int eidx, int substep, bf16* sA, bf16* sB)
{
  const int tid = threadIdx.x;
  const int lane = tid & 63, wv = tid >> 6, wm = wv & 1, wn = wv >> 1;
  const int fr = lane & 15, quad = lane >> 4;
  const int r0 = tid >> 5;                       // staging row base (8-row stride per load)
  const int cg = (tid & 24) | ((tid & 7) ^ (r0 & 7));  // swizzled source col-granule
  const int ntn = N >> 6;
  const int ntiles = (M >> 5) * ntn;
  const int nc = K >> 8;
  const int arow = wm*16 + fr, asw = arow & 7, abase = arow*32;
  const int brow0 = wn*32 + fr, bsw = brow0 & 7;
  const int bbase0 = brow0*32, bbase1 = (brow0+16)*32;

  for (int t = blockIdx.x; t < ntiles; t += NB){
    const int m0 = (t / ntn) << 5, n0 = (t % ntn) << 6;
    const bf16* gA = A + (size_t)(m0 + r0) * lda + cg*8;
    const bf16* gB = W + (size_t)(n0 + r0) * ldw + cg*8;
    f32x4 acc0 = {0.f,0.f,0.f,0.f}, acc1 = {0.f,0.f,0.f,0.f};
    __builtin_amdgcn_s_barrier();   // all waves done reading LDS of previous tile
#pragma unroll
    for (int pre = 0; pre < 2; ++pre){           // prologue: chunks 0,1 in flight
      bf16* dA = sA + pre*8192 + wv*512;
      bf16* dB = sB + pre*16384 + wv*512;
      const int kb = pre << 8;
#pragma unroll
      for (int j=0;j<4;++j) async_cp16(gA + (size_t)(8*j)*lda + kb, dA + j*2048);
#pragma unroll
      for (int j=0;j<8;++j) async_cp16(gB + (size_t)(8*j)*ldw + kb, dB + j*2048);
    }
    for (int c = 0; c < nc; ++c){
      if (c + 1 < nc) WAITVM(12); else WAITVM(0);  // newest 12 = next chunk, keep in flight
      __builtin_amdgcn_s_barrier();                // all waves' chunk-c data resident
      const bf16* bA = sA + (c&1)*8192;
      const bf16* bB = sB + (c&1)*16384;
#pragma unroll
      for (int ki = 0; ki < 4; ++ki){
#pragma unroll
        for (int h = 0; h < 2; ++h){
          const int gq = h*4 + quad;
          short8 af = *(const short8*)&bA[(abase + ki*8 + (gq ^ asw))*8];
          short8 b0 = *(const short8*)&bB[(bbase0 + ki*8 + (gq ^ bsw))*8];
          short8 b1 = *(const short8*)&bB[(bbase1 + ki*8 + (gq ^ bsw))*8];
          acc0 = __builtin_amdgcn_mfma_f32_16x16x32_bf16(af, b0, acc0, 0,0,0);
          acc1 = __builtin_amdgcn_mfma_f32_16x16x32_bf16(af, b1, acc1, 0,0,0);
        }
      }
      if (c + 2 < nc){
        __builtin_amdgcn_s_barrier();              // all waves done reading buf (c&1)
        bf16* dA = sA + (c&1)*8192 + wv*512;
        bf16* dB = sB + (c&1)*16384 + wv*512;
        const int kb = (c+2) << 8;
#pragma unroll
        for (int j=0;j<4;++j) async_cp16(gA + (size_t)(8*j)*lda + kb, dA + j*2048);
#pragma unroll
        for (int j=0;j<8;++j) async_cp16(gB + (size_t)(8*j)*ldw + kb, dB + j*2048);
      }
    }
    // C/D: col = lane&15, row = quad*4 + reg (m89-verified).
    const int rbase = m0 + wm*16 + quad*4;
#pragma unroll
    for (int tile = 0; tile < 2; ++tile){
      f32x4 av = tile ? acc1 : acc0;
      const int col = n0 + wn*32 + tile*16 + fr;
      const float bv = bias[col];
#pragma unroll
      for (int i = 0; i < 4; ++i){
        const int row = rbase + i;
        float v = av[i] + bv;
        if (MODE == MODE_SWISH1){
          v += tcur[row] * w1t[col];
          outb[(size_t)row*ldo + col] = __float2bfloat16(v * sigm(v));
        } else if (MODE == MODE_SWISH){
          outb[(size_t)row*ldo + col] = __float2bfloat16(v * sigm(v));
        } else if (MODE == MODE_F32){
          outf[(size_t)row*ldo + col] = v;
        } else {  // RK4
          const int hi = row*H_ + col;
          const float dt = dtbuf[row];
          const float ka = (eidx==1) ? v : kaccb[hi] + ((eidx==4)?1.f:2.f)*v;
          if (eidx < 4){
            kaccb[hi] = ka;
            const float amul = (eidx==3)?1.f:0.5f;
            wbuf[row*H_ + col] = __float2bfloat16(hbuf[hi] + amul*dt*v);
          } else {
            const float hn = hbuf[hi] + dt*(1.f/6.f)*ka;
            hbuf[hi] = hn;
            wbuf[row*H_ + col] = __float2bfloat16(hn);
          }
        }
      }
    }
    if (MODE == MODE_RK4 && n0 == 0 && tid < 32){
      const int r = m0 + tid;
      const float ce = (eidx<=2) ? ((float)substep+0.5f) : ((float)substep+1.f);
      tcur[r] = t0buf[r] + dtbuf[r]*ce;
    }
  }
}

__global__ __launch_bounds__(NT, 1) void persist_k(
    const bf16* __restrict__ xbf, const bf16* __restrict__ Wihb, const bf16* __restrict__ Whhb,
    const bf16* __restrict__ W1hb, const bf16* __restrict__ W2b, const bf16* __restrict__ W3b,
    const bf16* __restrict__ Woutb,
    const float* __restrict__ bih, const float* __restrict__ bhh, const float* __restrict__ b1,
    const float* __restrict__ b2, const float* __restrict__ b3, const float* __restrict__ bout,
    const float* __restrict__ ts,
    bf16* wbuf, bf16* z1, bf16* z2,
    float* hbuf, float* kaccb, float* gi, float* gh,
    float* t0b, float* dtb, float* tcur, const float* w1t,
    float* dout, unsigned* barcnt)
{
  extern __shared__ __align__(16) bf16 smem[];
  bf16* sA = smem;            // 2 x 8192 elems  (32x256 per buffer)
  bf16* sB = smem + 16384;    // 2 x 16384 elems (64x256 per buffer)
  unsigned bt = 0;
  auto BAR = [&](){ bt += NB; grid_bar(barcnt, bt); };

  // gi = x @ Wih^T + bih for all steps at once: (4096,1536), K=512.
  run_gemm<MODE_F32>(B_*T_, 3*H_, D_, xbf, D_, Wihb, D_, bih, gi, nullptr, 3*H_,
                     hbuf,kaccb,wbuf,dtb,t0b,tcur,w1t,0,0,sA,sB);
  BAR();
  for (int s = 0; s < T_; ++s){
    for (int n = 0; n < NSTEPS_; ++n){
      for (int e = 1; e <= 4; ++e){
        run_gemm<MODE_SWISH1>(B_, 1024, 512, wbuf, H_, W1hb, 512, b1, nullptr, z1, 1024,
                              hbuf,kaccb,wbuf,dtb,t0b,tcur,w1t,0,0,sA,sB);
        BAR();
        run_gemm<MODE_SWISH>(B_, 1024, 1024, z1, 1024, W2b, 1024, b2, nullptr, z2, 1024,
                             hbuf,kaccb,wbuf,dtb,t0b,tcur,w1t,0,0,sA,sB);
        BAR();
        run_gemm<MODE_RK4>(B_, H_, 1024, z2, 1024, W3b, 1024, b3, nullptr, nullptr, 0,
                           hbuf,kaccb,wbuf,dtb,t0b,tcur,w1t,e,n,sA,sB);
        BAR();
      }
    }
    run_gemm<MODE_F32>(B_, 3*H_, H_, wbuf, H_, Whhb, H_, bhh, gh, nullptr, 3*H_,
                       hbuf,kaccb,wbuf,dtb,t0b,tcur,w1t,0,0,sA,sB);
    BAR();
    // GRU gate combine + next-step time setup (elementwise).
    for (int idx = blockIdx.x*NT + threadIdx.x; idx < B_*H_; idx += NB*NT){
      int r = idx >> 9, c = idx & (H_-1);
      const size_t gib = (size_t)((r<<3)+s)*(3*H_);
      const size_t ghb2 = (size_t)r*(3*H_);
      float ir=gi[gib+c], iz=gi[gib+H_+c], inn=gi[gib+2*H_+c];
      float hr=gh[ghb2+c], hz=gh[ghb2+H_+c], hn=gh[ghb2+2*H_+c];
      float rg=sigm(ir+hr), zg=sigm(iz+hz);
      float ng=tanhf(inn+rg*hn);
      float hv=(1.f-zg)*ng+zg*hbuf[idx];
      hbuf[idx]=hv;
      wbuf[idx]=__float2bfloat16(hv);
      if (c==0){
        float t0n=ts[r*T_+s];
        float t1=(s<T_-1)?ts[r*T_+s+1]:t0n;
        t0b[r]=t0n; tcur[r]=t0n; dtb[r]=(t1-t0n)*0.25f;
      }
    }
    BAR();
  }
  run_gemm<MODE_F32>(B_, 128, H_, wbuf, H_, Woutb, H_, bout, dout, nullptr, 128,
                     hbuf,kaccb,wbuf,dtb,t0b,tcur,w1t,0,0,sA,sB);
  for (int idx = blockIdx.x*NT + threadIdx.x; idx < B_*H_; idx += NB*NT){
    dout[B_*128 + idx] = hbuf[idx];
    dout[B_*128 + B_*H_ + idx] = 0.f;
  }
}

// ---- prep kernels ----
__global__ void conv_k(const float* __restrict__ in, bf16* __restrict__ out,
                       int rows, int kin, int kout)
{
  int idx = blockIdx.x * 256 + threadIdx.x;
  if (idx >= rows * kout) return;
  int r = idx / kout, k = idx - r * kout;
  out[idx] = __float2bfloat16(k < kin ? in[(size_t)r * kin + k] : 0.f);
}

__global__ void w1t_k(const float* __restrict__ W1, float* __restrict__ w1t)
{
  int i = blockIdx.x * 256 + threadIdx.x;
  if (i < 1024) w1t[i] = W1[(size_t)i * 513 + 512];
}

__global__ void init_k(bf16* __restrict__ wbuf, float* __restrict__ hbuf,
                       float* __restrict__ t0buf, float* __restrict__ dtbuf,
                       float* __restrict__ tcur, const float* __restrict__ ts,
                       unsigned* __restrict__ barcnt)
{
  int idx = blockIdx.x * 256 + threadIdx.x;  // B_*H_
  int r = idx >> 9;
  wbuf[idx] = __float2bfloat16(0.f);
  hbuf[idx] = 0.f;
  if ((idx & (H_ - 1)) == 0) {
    float t0 = ts[r * T_];
    t0buf[r] = t0; tcur[r] = t0; dtbuf[r] = 0.f;
  }
  if (idx == 0) barcnt[0] = 0;
}

extern "C" void kernel_launch(void* const* d_in, const int* in_sizes, int n_in,
                              void* d_out, int out_size, void* d_ws, size_t ws_size,
                              hipStream_t stream)
{
  const float* x    = (const float*)d_in[0];
  const float* ts   = (const float*)d_in[1];
  const float* Wih  = (const float*)d_in[2];
  const float* Whh  = (const float*)d_in[3];
  const float* bih  = (const float*)d_in[4];
  const float* bhh  = (const float*)d_in[5];
  const float* Wout = (const float*)d_in[6];
  const float* bout = (const float*)d_in[7];
  const float* W1   = (const float*)d_in[8];
  const float* b1   = (const float*)d_in[9];
  const float* W2   = (const float*)d_in[10];
  const float* b2   = (const float*)d_in[11];
  const float* W3   = (const float*)d_in[12];
  const float* b3   = (const float*)d_in[13];

  char* ws = (char*)d_ws;
  size_t off = 0;
  auto alloc = [&](size_t n) { void* p = ws + off; off += (n + 255) & ~(size_t)255; return p; };

  bf16* xbf   = (bf16*)alloc((size_t)B_ * T_ * D_ * 2);
  bf16* Wihb  = (bf16*)alloc((size_t)3 * H_ * D_ * 2);
  bf16* Whhb  = (bf16*)alloc((size_t)3 * H_ * H_ * 2);
  bf16* W1hb  = (bf16*)alloc((size_t)1024 * 512 * 2);
  bf16* W2b   = (bf16*)alloc((size_t)1024 * 1024 * 2);
  bf16* W3b   = (bf16*)alloc((size_t)H_ * 1024 * 2);
  bf16* Woutb = (bf16*)alloc((size_t)128 * H_ * 2);
  bf16* wbuf  = (bf16*)alloc((size_t)B_ * H_ * 2);
  bf16* z1    = (bf16*)alloc((size_t)B_ * 1024 * 2);
  bf16* z2    = (bf16*)alloc((size_t)B_ * 1024 * 2);
  float* hbuf  = (float*)alloc((size_t)B_ * H_ * 4);
  float* kaccb = (float*)alloc((size_t)B_ * H_ * 4);
  float* gi    = (float*)alloc((size_t)B_ * T_ * 3 * H_ * 4);
  float* gh    = (float*)alloc((size_t)B_ * 3 * H_ * 4);
  float* t0b   = (float*)alloc((size_t)B_ * 4);
  float* dtb   = (float*)alloc((size_t)B_ * 4);
  float* tcur  = (float*)alloc((size_t)B_ * 4);
  float* w1t   = (float*)alloc((size_t)1024 * 4);
  unsigned* barcnt = (unsigned*)alloc(256);

  auto conv = [&](const float* in, bf16* out, int rows, int kin, int kout) {
    int n = rows * kout;
    conv_k<<<(n + 255) / 256, 256, 0, stream>>>(in, out, rows, kin, kout);
  };
  conv(x, xbf, B_ * T_, D_, D_);
  conv(Wih, Wihb, 3 * H_, D_, D_);
  conv(Whh, Whhb, 3 * H_, H_, H_);
  conv(W1, W1hb, 1024, 513, 512);   // cols 0..511 (t col handled via w1t rank-1 term)
  conv(W2, W2b, 1024, 1024, 1024);
  conv(W3, W3b, 512, 1024, 1024);
  conv(Wout, Woutb, 128, H_, H_);
  w1t_k<<<4, 256, 0, stream>>>(W1, w1t);
  init_k<<<(B_ * H_) / 256, 256, 0, stream>>>(wbuf, hbuf, t0b, dtb, tcur, ts, barcnt);

  static bool attr_set = false;
  if (!attr_set) {
    (void)hipFuncSetAttribute((const void*)persist_k,
                              hipFuncAttributeMaxDynamicSharedMemorySize, 98304);
    attr_set = true;
  }
  persist_k<<<NB, NT, 98304, stream>>>(
      xbf, Wihb, Whhb, W1hb, W2b, W3b, Woutb,
      bih, bhh, b1, b2, b3, bout, ts,
      wbuf, z1, z2, hbuf, kaccb, gi, gh,
      t0b, dtb, tcur, w1t, (float*)d_out, barcnt);
}

// Round 4
// 8646.326 us; speedup vs baseline: 2.4002x; 2.4002x over previous
//
#include <hip/hip_runtime.h>
#include <hip/hip_bf16.h>
#include <stdint.h>

// RecognitionODEGRU R3 — fence-free team pipeline.
// 8 teams x 64 rows; 32 blocks/team N-split every layer. Weight slices are
// LDS-resident (read once). Cross-block activation handoff via agent-scope
// relaxed atomic load/store (L3-coherent, no L2 fences — R2's __threadfence
// cost ~50us/phase). Monotone arrive counters per team; h/kacc in registers.
//
// Shapes: B=512, T=8, D=512, H=512, NSTEPS=4.
// d_out: outs[-1] (512,128) | h (512,512) | c=zeros (512,512), f32.

#define B_ 512
#define T_ 8
#define H_ 512
#define D_ 512
#define NSTEPS_ 4

typedef short short8 __attribute__((ext_vector_type(8)));
typedef float f32x4 __attribute__((ext_vector_type(4)));
typedef __hip_bfloat16 bf16;

__device__ __forceinline__ float sigm(float x){ return 1.f/(1.f+__expf(-x)); }

#define MFMA16(a,b,c) __builtin_amdgcn_mfma_f32_16x16x32_bf16((a),(b),(c),0,0,0)
#define ALD(p)   __hip_atomic_load((p), __ATOMIC_RELAXED, __HIP_MEMORY_SCOPE_AGENT)
#define AST(p,v) __hip_atomic_store((p),(v),__ATOMIC_RELAXED,__HIP_MEMORY_SCOPE_AGENT)

__device__ __forceinline__ short8 mk8(uint32_t u0,uint32_t u1,uint32_t u2,uint32_t u3){
  union{ uint32_t u[4]; short8 s; } cv;
  cv.u[0]=u0; cv.u[1]=u1; cv.u[2]=u2; cv.u[3]=u3; return cv.s;
}
// Coherent A-fragment: 16B as 4 agent-scope uint loads (2 bf16 each).
__device__ __forceinline__ short8 afragA(const uint32_t* b, int idx){
  return mk8(ALD(b+idx),ALD(b+idx+1),ALD(b+idx+2),ALD(b+idx+3));
}

__device__ __forceinline__ void wait_ge(unsigned* c, unsigned tgt, int* dead){
  if (threadIdx.x==0){
    if (!*dead){
      int it=0;
      while (ALD(c) < tgt){
        __builtin_amdgcn_s_sleep(2);
        if (++it > 30000000){ *dead=1; break; }  // ~4s valve: terminate, fail visibly
      }
    }
  }
  __syncthreads();
}
__device__ __forceinline__ void publish(unsigned* c){
  __syncthreads();  // drains all waves' outstanding stores (vmcnt) before signal
  if (threadIdx.x==0) __hip_atomic_fetch_add(c,1u,__ATOMIC_RELAXED,__HIP_MEMORY_SCOPE_AGENT);
}

// LDS layout (dynamic):
//  W1s: 32 x 520 bf16   @ 0        (33280 B)   ld 520 -> 2-way bank alias (free)
//  W2s: 32 x 1032 bf16  @ 33280    (66048 B)
//  W3s: 16 x 1032 bf16  @ 99328    (33024 B)
//  scr: 64 x 34 bf16    @ 132352   (4352 B)    epilogue repack scratch
//  t0s/dts/tcs: 3 x 64 f32 @ 136704 (768 B)
//  dead: int            @ 137472
__global__ __launch_bounds__(256,1) void persist_k(
    const bf16* __restrict__ W1hb, const bf16* __restrict__ W2b,
    const bf16* __restrict__ W3b,  const bf16* __restrict__ Woutb,
    const bf16* __restrict__ Wcb,  const bf16* __restrict__ xbf,
    const float* __restrict__ b1,  const float* __restrict__ b2,
    const float* __restrict__ b3,  const float* __restrict__ bout,
    const float* __restrict__ bcb, const float* __restrict__ w1t,
    const float* __restrict__ ts,
    bf16* wbufs, bf16* z1bufs, bf16* z2bufs, float* gbufs,
    unsigned* cnts, float* dout)
{
  extern __shared__ char smem[];
  bf16* W1s = (bf16*)smem;
  bf16* W2s = (bf16*)(smem + 33280);
  bf16* W3s = (bf16*)(smem + 99328);
  bf16* scr = (bf16*)(smem + 132352);
  uint32_t* scru = (uint32_t*)(smem + 132352);
  float* t0s = (float*)(smem + 136704);
  float* dts = t0s + 64;
  float* tcs = dts + 64;
  int* dead = (int*)(smem + 137472);

  const int tid = threadIdx.x, lane = tid & 63, wv = tid >> 6;
  const int fr = lane & 15, quad = lane >> 4;
  const int g = blockIdx.x >> 5, i = blockIdx.x & 31;
  const int gbase = g * 64;
  const int mh = wv >> 1, nn = wv & 1;   // z1/z2 role: m-half, n-tile
  const int nh = wv & 1;                 // gates: n-half (mh reused)

  bf16* wg  = wbufs  + (size_t)g * (64 * 512);
  bf16* z1g = z1bufs + (size_t)g * (64 * 1024);
  bf16* z2g = z2bufs + (size_t)g * (64 * 1024);
  float* gg = gbufs  + (size_t)g * (64 * 2048);
  uint32_t* wg32  = (uint32_t*)wg;
  uint32_t* z1g32 = (uint32_t*)z1g;
  uint32_t* z2g32 = (uint32_t*)z2g;
  unsigned* cw  = cnts + g * 128;
  unsigned* cz1 = cw + 32;
  unsigned* cz2 = cw + 64;
  unsigned* cgt = cw + 96;

  // ---- load weight slices into LDS (once) ----
  for (int u = tid; u < 32 * 64; u += 256){
    int r = u >> 6, c8 = u & 63;
    *(short8*)&W1s[r*520 + c8*8] = *(const short8*)&W1hb[(size_t)(32*i + r)*512 + c8*8];
  }
  for (int u = tid; u < 32 * 128; u += 256){
    int r = u >> 7, c8 = u & 127;
    *(short8*)&W2s[r*1032 + c8*8] = *(const short8*)&W2b[(size_t)(32*i + r)*1024 + c8*8];
  }
  for (int u = tid; u < 16 * 128; u += 256){
    int r = u >> 7, c8 = u & 127;
    *(short8*)&W3s[r*1032 + c8*8] = *(const short8*)&W3b[(size_t)(16*i + r)*1024 + c8*8];
  }
  if (tid < 64){
    float t0 = ts[(gbase + tid) * T_];
    t0s[tid] = t0; tcs[tid] = t0; dts[tid] = 0.f;
  }
  if (tid == 0) *dead = 0;
  __syncthreads();

  // per-lane bias preloads
  const float b1v[2]  = { b1[32*i + fr],  b1[32*i + 16 + fr] };
  const float b2v[2]  = { b2[32*i + fr],  b2[32*i + 16 + fr] };
  const float b3v     = b3[16*i + fr];
  const float w1tv[2] = { w1t[32*i + fr], w1t[32*i + 16 + fr] };
  float bcv[4];
#pragma unroll
  for (int nt = 0; nt < 4; ++nt) bcv[nt] = bcb[64*i + nt*16 + fr];

  float hreg[4] = {0.f,0.f,0.f,0.f}, kacc[4] = {0.f,0.f,0.f,0.f};
  unsigned tw = 32, tz1 = 32, tz2 = 32, tg = 32;

  for (int s = 0; s < T_; ++s){
    for (int sub = 0; sub < NSTEPS_; ++sub){
      for (int e = 1; e <= 4; ++e){
        // ================= z1 = swish(w @ W1^T + t*w1t + b1) =================
        wait_ge(cw, tw, dead);
        {
          f32x4 acc0 = {0,0,0,0}, acc1 = {0,0,0,0};
          const int nl = nn*16 + fr;
#pragma unroll
          for (int k = 0; k < 16; ++k){
            short8 b  = *(const short8*)&W1s[nl*520 + k*32 + quad*8];
            short8 a0 = afragA(wg32, (mh*32 + fr)*256 + k*16 + quad*4);
            short8 a1 = afragA(wg32, (mh*32 + 16 + fr)*256 + k*16 + quad*4);
            acc0 = MFMA16(a0, b, acc0);
            acc1 = MFMA16(a1, b, acc1);
          }
          const int colc = nn*16 + fr;
          const float bv = b1v[nn], wt = w1tv[nn];
#pragma unroll
          for (int j = 0; j < 4; ++j){
            int r0 = mh*32 + quad*4 + j, r1 = r0 + 16;
            float v0 = acc0[j] + bv + tcs[r0]*wt;
            float v1 = acc1[j] + bv + tcs[r1]*wt;
            scr[r0*34 + colc] = __float2bfloat16(v0 * sigm(v0));
            scr[r1*34 + colc] = __float2bfloat16(v1 * sigm(v1));
          }
          __syncthreads();
#pragma unroll
          for (int jj = 0; jj < 4; ++jj){
            int u = tid*4 + jj; int r = u >> 4, cu = u & 15;
            AST(z1g32 + r*512 + 16*i + cu, scru[r*17 + cu]);
          }
          publish(cz1);
        }
        // ================= z2 = swish(z1 @ W2^T + b2) =================
        wait_ge(cz1, tz1, dead); tz1 += 32;
        {
          f32x4 acc0 = {0,0,0,0}, acc1 = {0,0,0,0};
          const int nl = nn*16 + fr;
#pragma unroll 8
          for (int k = 0; k < 32; ++k){
            short8 b  = *(const short8*)&W2s[nl*1032 + k*32 + quad*8];
            short8 a0 = afragA(z1g32, (mh*32 + fr)*512 + k*16 + quad*4);
            short8 a1 = afragA(z1g32, (mh*32 + 16 + fr)*512 + k*16 + quad*4);
            acc0 = MFMA16(a0, b, acc0);
            acc1 = MFMA16(a1, b, acc1);
          }
          const int colc = nn*16 + fr;
          const float bv = b2v[nn];
#pragma unroll
          for (int j = 0; j < 4; ++j){
            int r0 = mh*32 + quad*4 + j, r1 = r0 + 16;
            float v0 = acc0[j] + bv, v1 = acc1[j] + bv;
            scr[r0*34 + colc] = __float2bfloat16(v0 * sigm(v0));
            scr[r1*34 + colc] = __float2bfloat16(v1 * sigm(v1));
          }
          __syncthreads();
#pragma unroll
          for (int jj = 0; jj < 4; ++jj){
            int u = tid*4 + jj; int r = u >> 4, cu = u & 15;
            AST(z2g32 + r*512 + 16*i + cu, scru[r*17 + cu]);
          }
          publish(cz2);
        }
        // ================= k = z2 @ W3^T + b3 ; RK4 in registers =================
        wait_ge(cz2, tz2, dead); tz2 += 32;
        {
          f32x4 acc = {0,0,0,0};
#pragma unroll 8
          for (int k = 0; k < 32; ++k){
            short8 b = *(const short8*)&W3s[fr*1032 + k*32 + quad*8];
            short8 a = afragA(z2g32, (wv*16 + fr)*512 + k*16 + quad*4);
            acc = MFMA16(a, b, acc);
          }
#pragma unroll
          for (int j = 0; j < 4; ++j){
            int row = wv*16 + quad*4 + j;
            float v = acc[j] + b3v;
            float dtv = dts[row];
            float ka = (e == 1) ? v : kacc[j] + ((e == 4) ? 1.f : 2.f) * v;
            float wnew;
            if (e < 4){
              kacc[j] = ka;
              wnew = hreg[j] + ((e == 3) ? 1.f : 0.5f) * dtv * v;
            } else {
              hreg[j] = hreg[j] + dtv * (1.f/6.f) * ka;
              wnew = hreg[j];
            }
            scr[row*34 + fr] = __float2bfloat16(wnew);
          }
          __syncthreads();
#pragma unroll
          for (int jj = 0; jj < 2; ++jj){
            int u = tid*2 + jj; int r = u >> 3, cu = u & 7;
            AST(wg32 + r*256 + 8*i + cu, scru[r*17 + cu]);
          }
          if (tid < 64){
            float ce = (e <= 2) ? ((float)sub + 0.5f) : ((float)sub + 1.f);
            tcs[tid] = t0s[tid] + dts[tid] * ce;
          }
          publish(cw);
          tw += 32;
        }
      }
    }
    // ================= gates: g = [w|x_s] @ Wc^T + bc  (N=2048: r|z|hn|in) =================
    wait_ge(cw, tw, dead);
    {
      f32x4 ac[4] = {{0,0,0,0},{0,0,0,0},{0,0,0,0},{0,0,0,0}};  // [nt2*2+mt2]
      // k 0..15: w-part (coherent); k 16..31: x-part (plain, prolog data)
#pragma unroll 4
      for (int k = 0; k < 16; ++k){
        short8 a0 = afragA(wg32, (mh*32 + fr)*256 + k*16 + quad*4);
        short8 a1 = afragA(wg32, (mh*32 + 16 + fr)*256 + k*16 + quad*4);
#pragma unroll
        for (int nt2 = 0; nt2 < 2; ++nt2){
          int nrow = 64*i + (nh*2 + nt2)*16 + fr;
          short8 b = *(const short8*)&Wcb[(size_t)nrow*1024 + k*32 + quad*8];
          ac[nt2*2]   = MFMA16(a0, b, ac[nt2*2]);
          ac[nt2*2+1] = MFMA16(a1, b, ac[nt2*2+1]);
        }
      }
#pragma unroll 4
      for (int k = 16; k < 32; ++k){
        const bf16* xr0 = xbf + ((size_t)(gbase + mh*32 + fr)*T_ + s)*512 + (k-16)*32 + quad*8;
        const bf16* xr1 = xbf + ((size_t)(gbase + mh*32 + 16 + fr)*T_ + s)*512 + (k-16)*32 + quad*8;
        short8 a0 = *(const short8*)xr0;
        short8 a1 = *(const short8*)xr1;
#pragma unroll
        for (int nt2 = 0; nt2 < 2; ++nt2){
          int nrow = 64*i + (nh*2 + nt2)*16 + fr;
          short8 b = *(const short8*)&Wcb[(size_t)nrow*1024 + k*32 + quad*8];
          ac[nt2*2]   = MFMA16(a0, b, ac[nt2*2]);
          ac[nt2*2+1] = MFMA16(a1, b, ac[nt2*2+1]);
        }
      }
#pragma unroll
      for (int nt2 = 0; nt2 < 2; ++nt2){
        int nt = nh*2 + nt2;
        int col = 64*i + nt*16 + fr;
#pragma unroll
        for (int mt2 = 0; mt2 < 2; ++mt2){
#pragma unroll
          for (int j = 0; j < 4; ++j){
            int row = mh*32 + mt2*16 + quad*4 + j;
            AST(gg + (size_t)row*2048 + col, ac[nt2*2 + mt2][j] + bcv[nt]);
          }
        }
      }
      publish(cgt);
    }
    wait_ge(cgt, tg, dead); tg += 32;
    {
      const int c = 16*i + fr;
#pragma unroll
      for (int j = 0; j < 4; ++j){
        int row = wv*16 + quad*4 + j;
        float gr = ALD(gg + (size_t)row*2048 + c);
        float gz = ALD(gg + (size_t)row*2048 + 512 + c);
        float hn = ALD(gg + (size_t)row*2048 + 1024 + c);
        float in = ALD(gg + (size_t)row*2048 + 1536 + c);
        float r_ = sigm(gr), z_ = sigm(gz);
        float n_ = tanhf(in + r_ * hn);
        hreg[j] = (1.f - z_) * n_ + z_ * hreg[j];
        scr[row*34 + fr] = __float2bfloat16(hreg[j]);
      }
      __syncthreads();
#pragma unroll
      for (int jj = 0; jj < 2; ++jj){
        int u = tid*2 + jj; int r = u >> 3, cu = u & 7;
        AST(wg32 + r*256 + 8*i + cu, scru[r*17 + cu]);
      }
      if (tid < 64){
        float t0n = ts[(gbase + tid)*T_ + s];
        float t1  = (s < T_-1) ? ts[(gbase + tid)*T_ + s + 1] : t0n;
        t0s[tid] = t0n; tcs[tid] = t0n; dts[tid] = (t1 - t0n) * 0.25f;
      }
      publish(cw);
      tw += 32;
    }
  }
  // ================= final: out = h' @ Wout^T + bout ; h ; c=0 =================
  wait_ge(cw, tw, dead);
  if (i < 8){
    f32x4 acc = {0,0,0,0};
    const float bov = bout[16*i + fr];
#pragma unroll
    for (int k = 0; k < 16; ++k){
      short8 b = *(const short8*)&Woutb[(size_t)(16*i + fr)*512 + k*32 + quad*8];
      short8 a = afragA(wg32, (wv*16 + fr)*256 + k*16 + quad*4);
      acc = MFMA16(a, b, acc);
    }
#pragma unroll
    for (int j = 0; j < 4; ++j){
      int row = wv*16 + quad*4 + j;
      dout[(size_t)(gbase + row)*128 + 16*i + fr] = acc[j] + bov;
    }
  }
#pragma unroll
  for (int j = 0; j < 4; ++j){
    int row = wv*16 + quad*4 + j, col = 16*i + fr;
    dout[(size_t)B_*128 + (size_t)(gbase + row)*512 + col] = hreg[j];
    dout[(size_t)B_*128 + (size_t)B_*512 + (size_t)(gbase + row)*512 + col] = 0.f;
  }
}

// ---- prolog kernels ----
__global__ void conv_k(const float* __restrict__ in, bf16* __restrict__ out,
                       int rows, int kin, int kout)
{
  int idx = blockIdx.x * 256 + threadIdx.x;
  if (idx >= rows * kout) return;
  int r = idx / kout, k = idx - r * kout;
  out[idx] = __float2bfloat16(k < kin ? in[(size_t)r * kin + k] : 0.f);
}

__global__ void w1t_k(const float* __restrict__ W1, float* __restrict__ w1t)
{
  int i = blockIdx.x * 256 + threadIdx.x;
  if (i < 1024) w1t[i] = W1[(size_t)i * 513 + 512];
}

// Wc (2048x1024 bf16): rows [0:512]=r:[Whh_r|Wih_r], [512:1024]=z, [1024:1536]=[Whh_n|0],
// [1536:2048]=[0|Wih_n].  bc matches.
__global__ void wc_k(const float* __restrict__ Wih, const float* __restrict__ Whh,
                     const float* __restrict__ bih, const float* __restrict__ bhh,
                     bf16* __restrict__ Wcb, float* __restrict__ bcb)
{
  int idx = blockIdx.x * 256 + threadIdx.x;
  if (idx >= 2048 * 1024) return;
  int r = idx >> 10, k = idx & 1023;
  int chunk = r >> 9, rr = r & 511;
  float v;
  if (chunk == 0)      v = (k < 512) ? Whh[(size_t)rr*512 + k]        : Wih[(size_t)rr*512 + (k-512)];
  else if (chunk == 1) v = (k < 512) ? Whh[(size_t)(512+rr)*512 + k]  : Wih[(size_t)(512+rr)*512 + (k-512)];
  else if (chunk == 2) v = (k < 512) ? Whh[(size_t)(1024+rr)*512 + k] : 0.f;
  else                 v = (k < 512) ? 0.f : Wih[(size_t)(1024+rr)*512 + (k-512)];
  Wcb[idx] = __float2bfloat16(v);
  if (k == 0){
    if (chunk <= 1) bcb[r] = bih[chunk*512 + rr] + bhh[chunk*512 + rr];
    else if (chunk == 2) bcb[r] = bhh[1024 + rr];
    else bcb[r] = bih[1024 + rr];
  }
}

__global__ void init_k(bf16* __restrict__ wbufs, unsigned* __restrict__ cnts)
{
  int idx = blockIdx.x * 256 + threadIdx.x;
  if (idx < 8 * 64 * 512) wbufs[idx] = __float2bfloat16(0.f);
  if (idx < 8 * 128){
    int g = idx >> 7, off = idx & 127;
    cnts[g*128 + off] = (off == 0) ? 32u : 0u;  // cw pre-armed (initial w publication)
  }
}

extern "C" void kernel_launch(void* const* d_in, const int* in_sizes, int n_in,
                              void* d_out, int out_size, void* d_ws, size_t ws_size,
                              hipStream_t stream)
{
  const float* x    = (const float*)d_in[0];
  const float* ts   = (const float*)d_in[1];
  const float* Wih  = (const float*)d_in[2];
  const float* Whh  = (const float*)d_in[3];
  const float* bih  = (const float*)d_in[4];
  const float* bhh  = (const float*)d_in[5];
  const float* Wout = (const float*)d_in[6];
  const float* bout = (const float*)d_in[7];
  const float* W1   = (const float*)d_in[8];
  const float* b1   = (const float*)d_in[9];
  const float* W2   = (const float*)d_in[10];
  const float* b2   = (const float*)d_in[11];
  const float* W3   = (const float*)d_in[12];
  const float* b3   = (const float*)d_in[13];

  char* ws = (char*)d_ws;
  size_t off = 0;
  auto alloc = [&](size_t n){ void* p = ws + off; off += (n + 255) & ~(size_t)255; return p; };

  bf16* xbf   = (bf16*)alloc((size_t)B_ * T_ * D_ * 2);
  bf16* W1hb  = (bf16*)alloc((size_t)1024 * 512 * 2);
  bf16* W2b   = (bf16*)alloc((size_t)1024 * 1024 * 2);
  bf16* W3b   = (bf16*)alloc((size_t)512 * 1024 * 2);
  bf16* Woutb = (bf16*)alloc((size_t)128 * 512 * 2);
  bf16* Wcb   = (bf16*)alloc((size_t)2048 * 1024 * 2);
  float* bcb  = (float*)alloc((size_t)2048 * 4);
  float* w1t  = (float*)alloc((size_t)1024 * 4);
  bf16* wbufs  = (bf16*)alloc((size_t)8 * 64 * 512 * 2);
  bf16* z1bufs = (bf16*)alloc((size_t)8 * 64 * 1024 * 2);
  bf16* z2bufs = (bf16*)alloc((size_t)8 * 64 * 1024 * 2);
  float* gbufs = (float*)alloc((size_t)8 * 64 * 2048 * 4);
  unsigned* cnts = (unsigned*)alloc((size_t)8 * 128 * 4);

  auto conv = [&](const float* in, bf16* out, int rows, int kin, int kout){
    int n = rows * kout;
    conv_k<<<(n + 255) / 256, 256, 0, stream>>>(in, out, rows, kin, kout);
  };
  conv(x, xbf, B_ * T_, D_, D_);
  conv(W1, W1hb, 1024, 513, 512);
  conv(W2, W2b, 1024, 1024, 1024);
  conv(W3, W3b, 512, 1024, 1024);
  conv(Wout, Woutb, 128, 512, 512);
  w1t_k<<<4, 256, 0, stream>>>(W1, w1t);
  wc_k<<<(2048 * 1024) / 256, 256, 0, stream>>>(Wih, Whh, bih, bhh, Wcb, bcb);
  init_k<<<(8 * 64 * 512 + 255) / 256, 256, 0, stream>>>(wbufs, cnts);

  (void)hipFuncSetAttribute((const void*)persist_k,
                            hipFuncAttributeMaxDynamicSharedMemorySize, 139264);
  persist_k<<<256, 256, 139264, stream>>>(
      W1hb, W2b, W3b, Woutb, Wcb, xbf,
      b1, b2, b3, bout, bcb, w1t, ts,
      wbufs, z1bufs, z2bufs, gbufs, cnts, (float*)d_out);
}

// Round 5
// 5411.040 us; speedup vs baseline: 3.8353x; 1.5979x over previous
//
#include <hip/hip_runtime.h>
#include <hip/hip_bf16.h>
#include <stdint.h>

// RecognitionODEGRU R4 — 32 independent m-group pipelines x 8 n-blocks.
// Each block: 16 batch rows, weights streamed from L2 (plain cached loads,
// XCD-affine n-slices), activations handed off through LLC via 8B agent-scope
// relaxed atomics (R3 used 4B: 640 scalar LLC loads/thread/eval -> issue-bound).
// h and RK4 accumulators live in registers (C-fragment ownership is identical
// across k-GEMM, gates and final output). No cross-m synchronization.
//
// Shapes: B=512, T=8, D=512, H=512, NSTEPS=4.
// d_out: outs[-1] (512,128) | h (512,512) | c=zeros (512,512), f32.

#define B_ 512
#define T_ 8
#define H_ 512
#define D_ 512

typedef short short8 __attribute__((ext_vector_type(8)));
typedef float f32x4 __attribute__((ext_vector_type(4)));
typedef __hip_bfloat16 bf16;
typedef unsigned long long u64;

__device__ __forceinline__ float sigm(float x){ return 1.f/(1.f+__expf(-x)); }

#define MFMA16(a,b,c) __builtin_amdgcn_mfma_f32_16x16x32_bf16((a),(b),(c),0,0,0)
#define ALD4(p)   __hip_atomic_load((p), __ATOMIC_RELAXED, __HIP_MEMORY_SCOPE_AGENT)
#define ALD8(p)   __hip_atomic_load((const u64*)(p), __ATOMIC_RELAXED, __HIP_MEMORY_SCOPE_AGENT)
#define AST8(p,v) __hip_atomic_store((u64*)(p),(v),__ATOMIC_RELAXED,__HIP_MEMORY_SCOPE_AGENT)

// Coherent 16B A-fragment: two 8B agent-scope loads (global_load_dwordx2 sc0 sc1).
__device__ __forceinline__ short8 cfrag(const bf16* p){
  union{ u64 q[2]; short8 s; } cv;
  cv.q[0] = ALD8(p);
  cv.q[1] = ALD8(p + 4);
  return cv.s;
}

__device__ __forceinline__ void wait_ge(unsigned* c, unsigned tgt, int* dead){
  if (threadIdx.x == 0){
    if (!*dead){
      int it = 0;
      while (ALD4(c) < tgt){
        __builtin_amdgcn_s_sleep(1);
        if (++it > 50000000){ *dead = 1; break; }  // terminate visibly, no hang
      }
    }
  }
  __syncthreads();
}
__device__ __forceinline__ void publish(unsigned* c){
  __builtin_amdgcn_s_waitcnt(0);   // drain this thread's stores before signaling
  __syncthreads();
  if (threadIdx.x == 0)
    __hip_atomic_fetch_add(c, 1u, __ATOMIC_RELAXED, __HIP_MEMORY_SCOPE_AGENT);
}

__global__ __launch_bounds__(256, 1) void persist_k(
    const bf16* __restrict__ W1hb, const bf16* __restrict__ W2b,
    const bf16* __restrict__ W3b,  const bf16* __restrict__ Woutb,
    const bf16* __restrict__ Wcb2, const bf16* __restrict__ xbf,
    const float* __restrict__ b1,  const float* __restrict__ b2,
    const float* __restrict__ b3,  const float* __restrict__ bout,
    const float* __restrict__ bcb2,const float* __restrict__ w1t,
    const float* __restrict__ ts,
    bf16* wbuf, bf16* z1buf, bf16* z2buf,
    unsigned* cnts, float* dout)
{
  __shared__ __align__(16) bf16 scr[16 * 132];
  __shared__ float t0s[16], dts[16], tcs[16];
  __shared__ int dead;

  const int tid = threadIdx.x, lane = tid & 63, wv = tid >> 6;
  const int fr = lane & 15, quad = lane >> 4;
  const int nb = blockIdx.x & 7;        // same-nb blocks share an XCD (weight L2 reuse)
  const int mb = blockIdx.x >> 3;       // 32 independent row-group pipelines
  const int gm0 = mb * 16;

  unsigned* cz1 = cnts + (mb*4 + 0)*16;  // 64B-padded counters
  unsigned* cz2 = cnts + (mb*4 + 1)*16;
  unsigned* cw  = cnts + (mb*4 + 2)*16;
  unsigned* cgt = cnts + (mb*4 + 3)*16;

  if (tid < 16){
    float t0 = ts[(gm0 + tid)*T_];
    t0s[tid] = t0; tcs[tid] = t0; dts[tid] = 0.f;
  }
  if (tid == 0) dead = 0;
  __syncthreads();

  // per-lane constants
  float b1v[2], b2v[2], w1tv[2];
#pragma unroll
  for (int t = 0; t < 2; ++t){
    int col = 128*nb + 32*wv + 16*t + fr;
    b1v[t] = b1[col]; b2v[t] = b2[col]; w1tv[t] = w1t[col];
  }
  const float b3v = b3[64*nb + 16*wv + fr];
  float bcv[4];
#pragma unroll
  for (int g = 0; g < 4; ++g) bcv[g] = bcb2[nb*256 + g*64 + 16*wv + fr];
  const float bov = bout[16*nb + fr];

  // weight row pointers (plain cached loads)
  const bf16* w1r0 = W1hb + (size_t)(128*nb + 32*wv + fr)*512  + quad*8;
  const bf16* w1r1 = w1r0 + (size_t)16*512;
  const bf16* w2r0 = W2b  + (size_t)(128*nb + 32*wv + fr)*1024 + quad*8;
  const bf16* w2r1 = w2r0 + (size_t)16*1024;
  const bf16* w3r  = W3b  + (size_t)(64*nb + 16*wv + fr)*1024  + quad*8;
  const bf16* wor  = Woutb+ (size_t)(16*nb + fr)*512           + quad*8;
  const bf16* wcr0 = Wcb2 + (size_t)(nb*256 +   0 + 16*wv + fr)*1024 + quad*8;
  const bf16* wcr1 = Wcb2 + (size_t)(nb*256 +  64 + 16*wv + fr)*1024 + quad*8;
  const bf16* wcr2 = Wcb2 + (size_t)(nb*256 + 128 + 16*wv + fr)*1024 + quad*8;
  const bf16* wcr3 = Wcb2 + (size_t)(nb*256 + 192 + 16*wv + fr)*1024 + quad*8;
  // activation row pointers (coherent)
  const bf16* wrow  = wbuf  + (size_t)(gm0 + fr)*512  + quad*8;
  const bf16* z1row = z1buf + (size_t)(gm0 + fr)*1024 + quad*8;
  const bf16* z2row = z2buf + (size_t)(gm0 + fr)*1024 + quad*8;

  float hreg[4] = {0.f,0.f,0.f,0.f}, kacc[4] = {0.f,0.f,0.f,0.f};
  unsigned tz1 = 8, tz2 = 8, tw = 8, tg = 8;

  for (int s = 0; s < T_; ++s){
    for (int sub = 0; sub < 4; ++sub){
      for (int e = 1; e <= 4; ++e){
        // ================= z1 = swish(w @ W1^T + t*w1t + b1), K=512 =================
        wait_ge(cw, tw, &dead);
        {
          f32x4 a0 = {0,0,0,0}, a1 = {0,0,0,0};
#pragma unroll 4
          for (int k = 0; k < 16; ++k){
            short8 af = cfrag(wrow + k*32);
            a0 = MFMA16(af, *(const short8*)(w1r0 + k*32), a0);
            a1 = MFMA16(af, *(const short8*)(w1r1 + k*32), a1);
          }
#pragma unroll
          for (int j = 0; j < 4; ++j){
            int r = quad*4 + j;
            float v0 = a0[j] + b1v[0] + tcs[r]*w1tv[0];
            float v1 = a1[j] + b1v[1] + tcs[r]*w1tv[1];
            scr[r*132 + 32*wv      + fr] = __float2bfloat16(v0 * sigm(v0));
            scr[r*132 + 32*wv + 16 + fr] = __float2bfloat16(v1 * sigm(v1));
          }
          __syncthreads();
          {  // repack 16x128 -> coherent 16B/thread
            int r = tid >> 4, c = tid & 15;
            const u64* src = (const u64*)&scr[r*132 + c*8];
            u64* dst = (u64*)(z1buf + (size_t)(gm0 + r)*1024 + 128*nb + c*8);
            AST8(dst, src[0]); AST8(dst + 1, src[1]);
          }
          publish(cz1);
        }
        // ================= z2 = swish(z1 @ W2^T + b2), K=1024 =================
        wait_ge(cz1, tz1, &dead); tz1 += 8;
        {
          f32x4 a0 = {0,0,0,0}, a1 = {0,0,0,0};
#pragma unroll 4
          for (int k = 0; k < 32; ++k){
            short8 af = cfrag(z1row + k*32);
            a0 = MFMA16(af, *(const short8*)(w2r0 + k*32), a0);
            a1 = MFMA16(af, *(const short8*)(w2r1 + k*32), a1);
          }
#pragma unroll
          for (int j = 0; j < 4; ++j){
            int r = quad*4 + j;
            float v0 = a0[j] + b2v[0];
            float v1 = a1[j] + b2v[1];
            scr[r*132 + 32*wv      + fr] = __float2bfloat16(v0 * sigm(v0));
            scr[r*132 + 32*wv + 16 + fr] = __float2bfloat16(v1 * sigm(v1));
          }
          __syncthreads();
          {
            int r = tid >> 4, c = tid & 15;
            const u64* src = (const u64*)&scr[r*132 + c*8];
            u64* dst = (u64*)(z2buf + (size_t)(gm0 + r)*1024 + 128*nb + c*8);
            AST8(dst, src[0]); AST8(dst + 1, src[1]);
          }
          publish(cz2);
        }
        // ================= k = z2 @ W3^T + b3 ; RK4 in registers, K=1024 =================
        wait_ge(cz2, tz2, &dead); tz2 += 8;
        {
          f32x4 acc = {0,0,0,0};
#pragma unroll 4
          for (int k = 0; k < 32; ++k)
            acc = MFMA16(cfrag(z2row + k*32), *(const short8*)(w3r + k*32), acc);
#pragma unroll
          for (int j = 0; j < 4; ++j){
            int row = quad*4 + j;
            float v = acc[j] + b3v;
            float dtv = dts[row];
            float ka = (e == 1) ? v : kacc[j] + ((e == 4) ? 1.f : 2.f)*v;
            float wn;
            if (e < 4){ kacc[j] = ka; wn = hreg[j] + ((e == 3) ? 1.f : 0.5f)*dtv*v; }
            else      { hreg[j] = hreg[j] + dtv*(1.f/6.f)*ka; wn = hreg[j]; }
            scr[row*132 + 16*wv + fr] = __float2bfloat16(wn);
          }
          __syncthreads();
          if (tid < 128){  // repack 16x64
            int r = tid >> 3, c = tid & 7;
            const u64* src = (const u64*)&scr[r*132 + c*8];
            u64* dst = (u64*)(wbuf + (size_t)(gm0 + r)*512 + 64*nb + c*8);
            AST8(dst, src[0]); AST8(dst + 1, src[1]);
          }
          if (tid < 16){
            float ce = (e <= 2) ? ((float)sub + 0.5f) : ((float)sub + 1.f);
            tcs[tid] = t0s[tid] + dts[tid]*ce;
          }
          publish(cw); tw += 8;
        }
      }
    }
    // ================= gates: [w|x_s] @ Wc2^T, grouped r|z|hn|in per 64 cols =================
    wait_ge(cw, tw, &dead);
    f32x4 ac0 = {0,0,0,0}, ac1 = {0,0,0,0}, ac2 = {0,0,0,0}, ac3 = {0,0,0,0};
    {
      const bf16* xrow = xbf + ((size_t)(gm0 + fr)*T_ + s)*512 + quad*8;
#pragma unroll 2
      for (int k = 0; k < 16; ++k){
        short8 af = cfrag(wrow + k*32);
        ac0 = MFMA16(af, *(const short8*)(wcr0 + k*32), ac0);
        ac1 = MFMA16(af, *(const short8*)(wcr1 + k*32), ac1);
        ac2 = MFMA16(af, *(const short8*)(wcr2 + k*32), ac2);
        ac3 = MFMA16(af, *(const short8*)(wcr3 + k*32), ac3);
      }
#pragma unroll 2
      for (int k = 16; k < 32; ++k){
        short8 af = *(const short8*)(xrow + (k - 16)*32);
        ac0 = MFMA16(af, *(const short8*)(wcr0 + k*32), ac0);
        ac1 = MFMA16(af, *(const short8*)(wcr1 + k*32), ac1);
        ac2 = MFMA16(af, *(const short8*)(wcr2 + k*32), ac2);
        ac3 = MFMA16(af, *(const short8*)(wcr3 + k*32), ac3);
      }
      publish(cgt);  // this block finished READING w — combine may overwrite after all publish
    }
    wait_ge(cgt, tg, &dead); tg += 8;
    {
#pragma unroll
      for (int j = 0; j < 4; ++j){
        int row = quad*4 + j;
        float r_ = sigm(ac0[j] + bcv[0]);
        float z_ = sigm(ac1[j] + bcv[1]);
        float hn = ac2[j] + bcv[2];
        float in = ac3[j] + bcv[3];
        float n_ = tanhf(in + r_*hn);
        hreg[j] = (1.f - z_)*n_ + z_*hreg[j];
        scr[row*132 + 16*wv + fr] = __float2bfloat16(hreg[j]);
      }
      __syncthreads();
      if (tid < 128){
        int r = tid >> 3, c = tid & 7;
        const u64* src = (const u64*)&scr[r*132 + c*8];
        u64* dst = (u64*)(wbuf + (size_t)(gm0 + r)*512 + 64*nb + c*8);
        AST8(dst, src[0]); AST8(dst + 1, src[1]);
      }
      if (tid < 16){
        float t0n = ts[(gm0 + tid)*T_ + s];
        float t1  = (s < T_-1) ? ts[(gm0 + tid)*T_ + s + 1] : t0n;
        t0s[tid] = t0n; tcs[tid] = t0n; dts[tid] = (t1 - t0n)*0.25f;
      }
      publish(cw); tw += 8;
    }
  }
  // ================= final: out = h @ Wout^T + bout ; h ; c = 0 =================
  wait_ge(cw, tw, &dead);
  if (wv == 0){
    f32x4 acc = {0,0,0,0};
#pragma unroll 4
    for (int k = 0; k < 16; ++k)
      acc = MFMA16(cfrag(wrow + k*32), *(const short8*)(wor + k*32), acc);
#pragma unroll
    for (int j = 0; j < 4; ++j)
      dout[(size_t)(gm0 + quad*4 + j)*128 + 16*nb + fr] = acc[j] + bov;
  }
#pragma unroll
  for (int j = 0; j < 4; ++j){
    int row = gm0 + quad*4 + j, col = 64*nb + 16*wv + fr;
    dout[(size_t)B_*128 + (size_t)row*512 + col] = hreg[j];
    dout[(size_t)B_*128 + (size_t)B_*512 + (size_t)row*512 + col] = 0.f;
  }
}

// ---- prolog kernels ----
__global__ void conv_k(const float* __restrict__ in, bf16* __restrict__ out,
                       int rows, int kin, int kout)
{
  int idx = blockIdx.x*256 + threadIdx.x;
  if (idx >= rows*kout) return;
  int r = idx / kout, k = idx - r*kout;
  out[idx] = __float2bfloat16(k < kin ? in[(size_t)r*kin + k] : 0.f);
}

__global__ void w1t_k(const float* __restrict__ W1, float* __restrict__ w1t)
{
  int i = blockIdx.x*256 + threadIdx.x;
  if (i < 1024) w1t[i] = W1[(size_t)i*513 + 512];
}

// Wc2 row R = n*256 + g*64 + c (hidden col hc=64n+c), K: [0:512]=h-part, [512:1024]=x-part.
// g=0:r=[Whh_r|Wih_r], g=1:z, g=2:hn=[Whh_n|0], g=3:in=[0|Wih_n]. bcb2 matches.
__global__ void wc2_k(const float* __restrict__ Wih, const float* __restrict__ Whh,
                      const float* __restrict__ bih, const float* __restrict__ bhh,
                      bf16* __restrict__ Wcb2, float* __restrict__ bcb2)
{
  int idx = blockIdx.x*256 + threadIdx.x;
  if (idx >= 2048*1024) return;
  int R = idx >> 10, k = idx & 1023;
  int n = R >> 8, rem = R & 255, g = rem >> 6, c = rem & 63;
  int hc = n*64 + c;
  float v;
  if      (g == 0) v = (k < 512) ? Whh[(size_t)hc*512 + k]          : Wih[(size_t)hc*512 + k - 512];
  else if (g == 1) v = (k < 512) ? Whh[(size_t)(512+hc)*512 + k]    : Wih[(size_t)(512+hc)*512 + k - 512];
  else if (g == 2) v = (k < 512) ? Whh[(size_t)(1024+hc)*512 + k]   : 0.f;
  else             v = (k < 512) ? 0.f                               : Wih[(size_t)(1024+hc)*512 + k - 512];
  Wcb2[idx] = __float2bfloat16(v);
  if (k == 0){
    if      (g == 0) bcb2[R] = bih[hc] + bhh[hc];
    else if (g == 1) bcb2[R] = bih[512 + hc] + bhh[512 + hc];
    else if (g == 2) bcb2[R] = bhh[1024 + hc];
    else             bcb2[R] = bih[1024 + hc];
  }
}

__global__ void init_k(bf16* __restrict__ wbuf, unsigned* __restrict__ cnts)
{
  int idx = blockIdx.x*256 + threadIdx.x;
  if (idx < B_*H_) wbuf[idx] = __float2bfloat16(0.f);
  if (idx < 32*4*16){
    int st = (idx >> 4) & 3;
    cnts[idx] = (st == 2 && (idx & 15) == 0) ? 8u : 0u;  // cw pre-armed (w=0 published)
  }
}

extern "C" void kernel_launch(void* const* d_in, const int* in_sizes, int n_in,
                              void* d_out, int out_size, void* d_ws, size_t ws_size,
                              hipStream_t stream)
{
  const float* x    = (const float*)d_in[0];
  const float* ts   = (const float*)d_in[1];
  const float* Wih  = (const float*)d_in[2];
  const float* Whh  = (const float*)d_in[3];
  const float* bih  = (const float*)d_in[4];
  const float* bhh  = (const float*)d_in[5];
  const float* Wout = (const float*)d_in[6];
  const float* bout = (const float*)d_in[7];
  const float* W1   = (const float*)d_in[8];
  const float* b1   = (const float*)d_in[9];
  const float* W2   = (const float*)d_in[10];
  const float* b2   = (const float*)d_in[11];
  const float* W3   = (const float*)d_in[12];
  const float* b3   = (const float*)d_in[13];

  char* ws = (char*)d_ws;
  size_t off = 0;
  auto alloc = [&](size_t n){ void* p = ws + off; off += (n + 255) & ~(size_t)255; return p; };

  bf16* xbf   = (bf16*)alloc((size_t)B_*T_*D_*2);
  bf16* W1hb  = (bf16*)alloc((size_t)1024*512*2);
  bf16* W2b   = (bf16*)alloc((size_t)1024*1024*2);
  bf16* W3b   = (bf16*)alloc((size_t)512*1024*2);
  bf16* Woutb = (bf16*)alloc((size_t)128*512*2);
  bf16* Wcb2  = (bf16*)alloc((size_t)2048*1024*2);
  float* bcb2 = (float*)alloc((size_t)2048*4);
  float* w1t  = (float*)alloc((size_t)1024*4);
  bf16* wbuf  = (bf16*)alloc((size_t)B_*H_*2);
  bf16* z1buf = (bf16*)alloc((size_t)B_*1024*2);
  bf16* z2buf = (bf16*)alloc((size_t)B_*1024*2);
  unsigned* cnts = (unsigned*)alloc((size_t)32*4*16*4);

  auto conv = [&](const float* in, bf16* out, int rows, int kin, int kout){
    int n = rows*kout;
    conv_k<<<(n + 255)/256, 256, 0, stream>>>(in, out, rows, kin, kout);
  };
  conv(x, xbf, B_*T_, D_, D_);
  conv(W1, W1hb, 1024, 513, 512);   // col 512 handled via w1t rank-1 term
  conv(W2, W2b, 1024, 1024, 1024);
  conv(W3, W3b, 512, 1024, 1024);
  conv(Wout, Woutb, 128, 512, 512);
  w1t_k<<<4, 256, 0, stream>>>(W1, w1t);
  wc2_k<<<(2048*1024)/256, 256, 0, stream>>>(Wih, Whh, bih, bhh, Wcb2, bcb2);
  init_k<<<(B_*H_ + 255)/256, 256, 0, stream>>>(wbuf, cnts);

  persist_k<<<256, 256, 0, stream>>>(
      W1hb, W2b, W3b, Woutb, Wcb2, xbf,
      b1, b2, b3, bout, bcb2, w1t, ts,
      wbuf, z1buf, z2buf, cnts, (float*)d_out);
}

// Round 6
// 3366.645 us; speedup vs baseline: 6.1643x; 1.6073x over previous
//
#include <hip/hip_runtime.h>
#include <hip/hip_bf16.h>
#include <stdint.h>

// RecognitionODEGRU R5 — 16 chains (32 rows) x 8 n-blocks = 128 blocks.
// Per phase: activation slab staged ONCE into LDS via batched 8B agent-scope
// loads (R4 had 4x wave-redundant scattered coherent fragment loads), MFMA
// fragments via ds_read_b128, weights plain L2 loads with no wave redundancy
// (4x32-col wave split). Handoff protocol (LLC counters) unchanged from R4.
//
// Shapes: B=512, T=8, D=512, H=512, NSTEPS=4.
// d_out: outs[-1] (512,128) | h (512,512) | c=zeros (512,512), f32.

#define B_ 512
#define T_ 8
#define H_ 512
#define D_ 512

typedef short short8 __attribute__((ext_vector_type(8)));
typedef float f32x4 __attribute__((ext_vector_type(4)));
typedef __hip_bfloat16 bf16;
typedef unsigned long long u64;

__device__ __forceinline__ float sigm(float x){ return 1.f/(1.f+__expf(-x)); }

#define MFMA16(a,b,c) __builtin_amdgcn_mfma_f32_16x16x32_bf16((a),(b),(c),0,0,0)
#define ALD4(p)   __hip_atomic_load((p), __ATOMIC_RELAXED, __HIP_MEMORY_SCOPE_AGENT)
#define ALD8(p)   __hip_atomic_load((const u64*)(p), __ATOMIC_RELAXED, __HIP_MEMORY_SCOPE_AGENT)
#define AST8(p,v) __hip_atomic_store((u64*)(p),(v),__ATOMIC_RELAXED,__HIP_MEMORY_SCOPE_AGENT)

__device__ __forceinline__ void wait_ge(unsigned* c, unsigned tgt, int* dead){
  if (threadIdx.x == 0){
    if (!*dead){
      int it = 0;
      while (ALD4(c) < tgt){
        __builtin_amdgcn_s_sleep(1);
        if (++it > 50000000){ *dead = 1; break; }  // terminate visibly, no hang
      }
    }
  }
  __syncthreads();
}
__device__ __forceinline__ void publish(unsigned* c){
  __builtin_amdgcn_s_waitcnt(0);   // each wave drains its stores before barrier
  __syncthreads();
  if (threadIdx.x == 0)
    __hip_atomic_fetch_add(c, 1u, __ATOMIC_RELAXED, __HIP_MEMORY_SCOPE_AGENT);
}

// Coherent slab stage: CH 8B-chunks/thread, 2^SH chunks per row. Loads batched
// (tmp array) so the compiler keeps them in flight; then ds_write.
template<int CH, int SH>
__device__ __forceinline__ void stageC(bf16* lds, int lstr, const bf16* g, int gstr){
  u64 tmp[CH];
#pragma unroll
  for (int j = 0; j < CH; ++j){
    int idx = j*256 + threadIdx.x;
    tmp[j] = ALD8(g + (size_t)(idx >> SH)*gstr + (size_t)(idx & ((1<<SH)-1))*4);
  }
#pragma unroll
  for (int j = 0; j < CH; ++j){
    int idx = j*256 + threadIdx.x;
    *(u64*)&lds[(idx >> SH)*lstr + (idx & ((1<<SH)-1))*4] = tmp[j];
  }
}
// Plain (L2-cached) slab stage: CH 16B-chunks/thread, 2^SH chunks per row.
template<int CH, int SH>
__device__ __forceinline__ void stageP(bf16* lds, int lstr, const bf16* g, size_t gstr){
#pragma unroll
  for (int j = 0; j < CH; ++j){
    int idx = j*256 + threadIdx.x;
    *(short8*)&lds[(idx >> SH)*lstr + (idx & ((1<<SH)-1))*8] =
        *(const short8*)(g + (size_t)(idx >> SH)*gstr + (size_t)(idx & ((1<<SH)-1))*8);
  }
}

// LDS (dynamic): slab 32x1032 bf16 @0 (66048B) — stride 1032/520 both give free
// 2-way bank aliasing; scr 32x132 bf16 @66048 (8448B); t0s/dts/tcs @74496;
// dead @74880. Total 74884 B.
__global__ __launch_bounds__(256, 1) void persist_k(
    const bf16* __restrict__ W1hb, const bf16* __restrict__ W2b,
    const bf16* __restrict__ W3b,  const bf16* __restrict__ Woutb,
    const bf16* __restrict__ Wcb2, const bf16* __restrict__ xbf,
    const float* __restrict__ b1,  const float* __restrict__ b2,
    const float* __restrict__ b3,  const float* __restrict__ bout,
    const float* __restrict__ bcb2,const float* __restrict__ w1t,
    const float* __restrict__ ts,
    bf16* wbuf, bf16* z1buf, bf16* z2buf,
    unsigned* cnts, float* dout)
{
  extern __shared__ char smem[];
  bf16* slab = (bf16*)smem;
  bf16* scr  = (bf16*)(smem + 66048);
  uint32_t* scru = (uint32_t*)scr;
  float* t0s = (float*)(smem + 74496);
  float* dts = t0s + 32;
  float* tcs = dts + 32;
  int* dead  = (int*)(smem + 74880);

  const int tid = threadIdx.x, lane = tid & 63, wv = tid >> 6;
  const int fr = lane & 15, quad = lane >> 4;
  const int nb = blockIdx.x & 7;
  const int mb = blockIdx.x >> 3;     // 16 chains
  const int gm0 = mb * 32;

  unsigned* cz1 = cnts + mb*128;
  unsigned* cz2 = cz1 + 32;
  unsigned* cw  = cz1 + 64;
  unsigned* cgt = cz1 + 96;

  if (tid < 32){
    float t0 = ts[(gm0 + tid)*T_];
    t0s[tid] = t0; tcs[tid] = t0; dts[tid] = 0.f;
  }
  if (tid == 0) *dead = 0;
  __syncthreads();

  // per-lane constants (wave wv owns 32-col slice 32wv of the block's 128 cols)
  float b1v[2], b2v[2], w1tv[2];
#pragma unroll
  for (int t = 0; t < 2; ++t){
    int col = 128*nb + 32*wv + 16*t + fr;
    b1v[t] = b1[col]; b2v[t] = b2[col]; w1tv[t] = w1t[col];
  }
  const float b3v = b3[64*nb + 16*wv + fr];
  float bcv[4];
#pragma unroll
  for (int g = 0; g < 4; ++g) bcv[g] = bcb2[nb*256 + g*64 + 16*wv + fr];
  const float bov = bout[16*nb + fr];

  // weight row pointers (plain L2-cached; no wave redundancy)
  const bf16* w1p0 = W1hb + (size_t)(128*nb + 32*wv      + fr)*512  + quad*8;
  const bf16* w1p1 = W1hb + (size_t)(128*nb + 32*wv + 16 + fr)*512  + quad*8;
  const bf16* w2p0 = W2b  + (size_t)(128*nb + 32*wv      + fr)*1024 + quad*8;
  const bf16* w2p1 = W2b  + (size_t)(128*nb + 32*wv + 16 + fr)*1024 + quad*8;
  const bf16* w3p  = W3b  + (size_t)(64*nb + 16*wv + fr)*1024 + quad*8;
  const bf16* wop  = Woutb + (size_t)(16*nb + fr)*512 + quad*8;
  const bf16* wcp0 = Wcb2 + (size_t)(nb*256 +   0 + 16*wv + fr)*1024 + quad*8;
  const bf16* wcp1 = Wcb2 + (size_t)(nb*256 +  64 + 16*wv + fr)*1024 + quad*8;
  const bf16* wcp2 = Wcb2 + (size_t)(nb*256 + 128 + 16*wv + fr)*1024 + quad*8;
  const bf16* wcp3 = Wcb2 + (size_t)(nb*256 + 192 + 16*wv + fr)*1024 + quad*8;

  float hreg[2][4] = {{0,0,0,0},{0,0,0,0}}, kacc[2][4] = {{0,0,0,0},{0,0,0,0}};
  unsigned tz1 = 8, tz2 = 8, tw = 8, tg = 8;

  for (int s = 0; s < T_; ++s){
    for (int sub = 0; sub < 4; ++sub){
      for (int e = 1; e <= 4; ++e){
        // ===== z1 = swish(w @ W1^T + t*w1t + b1), K=512 =====
        wait_ge(cw, tw, dead);
        stageC<16,7>(slab, 520, wbuf + (size_t)gm0*512, 512);
        __syncthreads();
        {
          f32x4 a00={0,0,0,0}, a01={0,0,0,0}, a10={0,0,0,0}, a11={0,0,0,0};
#pragma unroll 4
          for (int k = 0; k < 16; ++k){
            short8 bf0 = *(const short8*)(w1p0 + k*32);
            short8 bf1 = *(const short8*)(w1p1 + k*32);
            short8 x0 = *(const short8*)&slab[(     fr)*520 + k*32 + quad*8];
            short8 x1 = *(const short8*)&slab[(16 + fr)*520 + k*32 + quad*8];
            a00 = MFMA16(x0, bf0, a00); a01 = MFMA16(x0, bf1, a01);
            a10 = MFMA16(x1, bf0, a10); a11 = MFMA16(x1, bf1, a11);
          }
#pragma unroll
          for (int j = 0; j < 4; ++j){
            int r0 = quad*4 + j, r1 = 16 + r0;
            float v00 = a00[j] + b1v[0] + tcs[r0]*w1tv[0];
            float v01 = a01[j] + b1v[1] + tcs[r0]*w1tv[1];
            float v10 = a10[j] + b1v[0] + tcs[r1]*w1tv[0];
            float v11 = a11[j] + b1v[1] + tcs[r1]*w1tv[1];
            scr[r0*132 + 32*wv      + fr] = __float2bfloat16(v00*sigm(v00));
            scr[r0*132 + 32*wv + 16 + fr] = __float2bfloat16(v01*sigm(v01));
            scr[r1*132 + 32*wv      + fr] = __float2bfloat16(v10*sigm(v10));
            scr[r1*132 + 32*wv + 16 + fr] = __float2bfloat16(v11*sigm(v11));
          }
          __syncthreads();
#pragma unroll
          for (int j = 0; j < 4; ++j){
            int idx = j*256 + tid, r = idx >> 5, c = idx & 31;
            AST8((u64*)(z1buf + (size_t)(gm0 + r)*1024 + 128*nb + c*4),
                 *(const u64*)&scr[r*132 + c*4]);
          }
          publish(cz1);
        }
        // ===== z2 = swish(z1 @ W2^T + b2), K=1024 =====
        wait_ge(cz1, tz1, dead); tz1 += 8;
        stageC<32,8>(slab, 1032, z1buf + (size_t)gm0*1024, 1024);
        __syncthreads();
        {
          f32x4 a00={0,0,0,0}, a01={0,0,0,0}, a10={0,0,0,0}, a11={0,0,0,0};
#pragma unroll 4
          for (int k = 0; k < 32; ++k){
            short8 bf0 = *(const short8*)(w2p0 + k*32);
            short8 bf1 = *(const short8*)(w2p1 + k*32);
            short8 x0 = *(const short8*)&slab[(     fr)*1032 + k*32 + quad*8];
            short8 x1 = *(const short8*)&slab[(16 + fr)*1032 + k*32 + quad*8];
            a00 = MFMA16(x0, bf0, a00); a01 = MFMA16(x0, bf1, a01);
            a10 = MFMA16(x1, bf0, a10); a11 = MFMA16(x1, bf1, a11);
          }
#pragma unroll
          for (int j = 0; j < 4; ++j){
            int r0 = quad*4 + j, r1 = 16 + r0;
            float v00 = a00[j] + b2v[0], v01 = a01[j] + b2v[1];
            float v10 = a10[j] + b2v[0], v11 = a11[j] + b2v[1];
            scr[r0*132 + 32*wv      + fr] = __float2bfloat16(v00*sigm(v00));
            scr[r0*132 + 32*wv + 16 + fr] = __float2bfloat16(v01*sigm(v01));
            scr[r1*132 + 32*wv      + fr] = __float2bfloat16(v10*sigm(v10));
            scr[r1*132 + 32*wv + 16 + fr] = __float2bfloat16(v11*sigm(v11));
          }
          __syncthreads();
#pragma unroll
          for (int j = 0; j < 4; ++j){
            int idx = j*256 + tid, r = idx >> 5, c = idx & 31;
            AST8((u64*)(z2buf + (size_t)(gm0 + r)*1024 + 128*nb + c*4),
                 *(const u64*)&scr[r*132 + c*4]);
          }
          publish(cz2);
        }
        // ===== k = z2 @ W3^T + b3 ; RK4 in registers, K=1024 =====
        wait_ge(cz2, tz2, dead); tz2 += 8;
        stageC<32,8>(slab, 1032, z2buf + (size_t)gm0*1024, 1024);
        __syncthreads();
        {
          f32x4 ak0={0,0,0,0}, ak1={0,0,0,0};
#pragma unroll 8
          for (int k = 0; k < 32; ++k){
            short8 bf0 = *(const short8*)(w3p + k*32);
            short8 x0 = *(const short8*)&slab[(     fr)*1032 + k*32 + quad*8];
            short8 x1 = *(const short8*)&slab[(16 + fr)*1032 + k*32 + quad*8];
            ak0 = MFMA16(x0, bf0, ak0); ak1 = MFMA16(x1, bf0, ak1);
          }
#pragma unroll
          for (int rt = 0; rt < 2; ++rt){
            f32x4 ak = rt ? ak1 : ak0;
#pragma unroll
            for (int j = 0; j < 4; ++j){
              int row = rt*16 + quad*4 + j;
              float v = ak[j] + b3v;
              float dtv = dts[row];
              float ka = (e == 1) ? v : kacc[rt][j] + ((e == 4) ? 1.f : 2.f)*v;
              float wn;
              if (e < 4){ kacc[rt][j] = ka; wn = hreg[rt][j] + ((e == 3) ? 1.f : 0.5f)*dtv*v; }
              else      { hreg[rt][j] = hreg[rt][j] + dtv*(1.f/6.f)*ka; wn = hreg[rt][j]; }
              scr[row*132 + 16*wv + fr] = __float2bfloat16(wn);
            }
          }
          __syncthreads();
#pragma unroll
          for (int j = 0; j < 2; ++j){
            int idx = j*256 + tid, r = idx >> 4, c = idx & 15;
            AST8((u64*)(wbuf + (size_t)(gm0 + r)*512 + 64*nb + c*4),
                 *(const u64*)&scr[r*132 + c*4]);
          }
          if (tid < 32){
            float ce = (e <= 2) ? ((float)sub + 0.5f) : ((float)sub + 1.f);
            tcs[tid] = t0s[tid] + dts[tid]*ce;
          }
          publish(cw); tw += 8;
        }
      }
    }
    // ===== gates: [w|x_s] @ Wc2^T (grouped r|z|hn|in per 64 cols), K=1024 =====
    wait_ge(cw, tw, dead);
    stageC<16,7>(slab, 1032, wbuf + (size_t)gm0*512, 512);
    stageP<8,6>(slab + 512, 1032, xbf + ((size_t)gm0*T_ + s)*512, (size_t)T_*512);
    __syncthreads();
    publish(cgt);   // w consumed (staged) — safe for others to see; we overwrite w below
    {
      f32x4 ag[4][2] = {{{0,0,0,0},{0,0,0,0}},{{0,0,0,0},{0,0,0,0}},
                        {{0,0,0,0},{0,0,0,0}},{{0,0,0,0},{0,0,0,0}}};
#pragma unroll 4
      for (int k = 0; k < 32; ++k){
        short8 x0 = *(const short8*)&slab[(     fr)*1032 + k*32 + quad*8];
        short8 x1 = *(const short8*)&slab[(16 + fr)*1032 + k*32 + quad*8];
        short8 bq0 = *(const short8*)(wcp0 + k*32);
        short8 bq1 = *(const short8*)(wcp1 + k*32);
        short8 bq2 = *(const short8*)(wcp2 + k*32);
        short8 bq3 = *(const short8*)(wcp3 + k*32);
        ag[0][0] = MFMA16(x0, bq0, ag[0][0]); ag[0][1] = MFMA16(x1, bq0, ag[0][1]);
        ag[1][0] = MFMA16(x0, bq1, ag[1][0]); ag[1][1] = MFMA16(x1, bq1, ag[1][1]);
        ag[2][0] = MFMA16(x0, bq2, ag[2][0]); ag[2][1] = MFMA16(x1, bq2, ag[2][1]);
        ag[3][0] = MFMA16(x0, bq3, ag[3][0]); ag[3][1] = MFMA16(x1, bq3, ag[3][1]);
      }
      wait_ge(cgt, tg, dead); tg += 8;   // all 8 blocks consumed old w
#pragma unroll
      for (int rt = 0; rt < 2; ++rt){
#pragma unroll
        for (int j = 0; j < 4; ++j){
          int row = rt*16 + quad*4 + j;
          float r_ = sigm(ag[0][rt][j] + bcv[0]);
          float z_ = sigm(ag[1][rt][j] + bcv[1]);
          float hn = ag[2][rt][j] + bcv[2];
          float in = ag[3][rt][j] + bcv[3];
          float n_ = tanhf(in + r_*hn);
          hreg[rt][j] = (1.f - z_)*n_ + z_*hreg[rt][j];
          scr[row*132 + 16*wv + fr] = __float2bfloat16(hreg[rt][j]);
        }
      }
      __syncthreads();
#pragma unroll
      for (int j = 0; j < 2; ++j){
        int idx = j*256 + tid, r = idx >> 4, c = idx & 15;
        AST8((u64*)(wbuf + (size_t)(gm0 + r)*512 + 64*nb + c*4),
             *(const u64*)&scr[r*132 + c*4]);
      }
      if (tid < 32){
        float t0n = ts[(gm0 + tid)*T_ + s];
        float t1  = (s < T_-1) ? ts[(gm0 + tid)*T_ + s + 1] : t0n;
        t0s[tid] = t0n; tcs[tid] = t0n; dts[tid] = (t1 - t0n)*0.25f;
      }
      publish(cw); tw += 8;
    }
  }
  // ===== final: out = h @ Wout^T + bout ; h ; c = 0 =====
  wait_ge(cw, tw, dead);
  stageC<16,7>(slab, 520, wbuf + (size_t)gm0*512, 512);
  __syncthreads();
  if (wv == 0){
    f32x4 ao0={0,0,0,0}, ao1={0,0,0,0};
#pragma unroll 4
    for (int k = 0; k < 16; ++k){
      short8 bf0 = *(const short8*)(wop + k*32);
      short8 x0 = *(const short8*)&slab[(     fr)*520 + k*32 + quad*8];
      short8 x1 = *(const short8*)&slab[(16 + fr)*520 + k*32 + quad*8];
      ao0 = MFMA16(x0, bf0, ao0); ao1 = MFMA16(x1, bf0, ao1);
    }
#pragma unroll
    for (int rt = 0; rt < 2; ++rt){
      f32x4 ao = rt ? ao1 : ao0;
#pragma unroll
      for (int j = 0; j < 4; ++j)
        dout[(size_t)(gm0 + rt*16 + quad*4 + j)*128 + 16*nb + fr] = ao[j] + bov;
    }
  }
#pragma unroll
  for (int rt = 0; rt < 2; ++rt){
#pragma unroll
    for (int j = 0; j < 4; ++j){
      int row = gm0 + rt*16 + quad*4 + j, col = 64*nb + 16*wv + fr;
      dout[(size_t)B_*128 + (size_t)row*512 + col] = hreg[rt][j];
      dout[(size_t)B_*128 + (size_t)B_*512 + (size_t)row*512 + col] = 0.f;
    }
  }
}

// ---- prolog kernels ----
__global__ void conv_k(const float* __restrict__ in, bf16* __restrict__ out,
                       int rows, int kin, int kout)
{
  int idx = blockIdx.x*256 + threadIdx.x;
  if (idx >= rows*kout) return;
  int r = idx / kout, k = idx - r*kout;
  out[idx] = __float2bfloat16(k < kin ? in[(size_t)r*kin + k] : 0.f);
}

__global__ void w1t_k(const float* __restrict__ W1, float* __restrict__ w1t)
{
  int i = blockIdx.x*256 + threadIdx.x;
  if (i < 1024) w1t[i] = W1[(size_t)i*513 + 512];
}

// Wc2 row R = n*256 + g*64 + c (hidden col hc=64n+c), K: [0:512]=h-part, [512:1024]=x-part.
__global__ void wc2_k(const float* __restrict__ Wih, const float* __restrict__ Whh,
                      const float* __restrict__ bih, const float* __restrict__ bhh,
                      bf16* __restrict__ Wcb2, float* __restrict__ bcb2)
{
  int idx = blockIdx.x*256 + threadIdx.x;
  if (idx >= 2048*1024) return;
  int R = idx >> 10, k = idx & 1023;
  int n = R >> 8, rem = R & 255, g = rem >> 6, c = rem & 63;
  int hc = n*64 + c;
  float v;
  if      (g == 0) v = (k < 512) ? Whh[(size_t)hc*512 + k]          : Wih[(size_t)hc*512 + k - 512];
  else if (g == 1) v = (k < 512) ? Whh[(size_t)(512+hc)*512 + k]    : Wih[(size_t)(512+hc)*512 + k - 512];
  else if (g == 2) v = (k < 512) ? Whh[(size_t)(1024+hc)*512 + k]   : 0.f;
  else             v = (k < 512) ? 0.f                               : Wih[(size_t)(1024+hc)*512 + k - 512];
  Wcb2[idx] = __float2bfloat16(v);
  if (k == 0){
    if      (g == 0) bcb2[R] = bih[hc] + bhh[hc];
    else if (g == 1) bcb2[R] = bih[512 + hc] + bhh[512 + hc];
    else if (g == 2) bcb2[R] = bhh[1024 + hc];
    else             bcb2[R] = bih[1024 + hc];
  }
}

__global__ void init_k(bf16* __restrict__ wbuf, unsigned* __restrict__ cnts)
{
  int idx = blockIdx.x*256 + threadIdx.x;
  if (idx < B_*H_) wbuf[idx] = __float2bfloat16(0.f);
  if (idx < 16*128){
    int off = idx & 127;
    cnts[idx] = (off == 64) ? 8u : 0u;   // cw pre-armed (initial w=0 published)
  }
}

extern "C" void kernel_launch(void* const* d_in, const int* in_sizes, int n_in,
                              void* d_out, int out_size, void* d_ws, size_t ws_size,
                              hipStream_t stream)
{
  const float* x    = (const float*)d_in[0];
  const float* ts   = (const float*)d_in[1];
  const float* Wih  = (const float*)d_in[2];
  const float* Whh  = (const float*)d_in[3];
  const float* bih  = (const float*)d_in[4];
  const float* bhh  = (const float*)d_in[5];
  const float* Wout = (const float*)d_in[6];
  const float* bout = (const float*)d_in[7];
  const float* W1   = (const float*)d_in[8];
  const float* b1   = (const float*)d_in[9];
  const float* W2   = (const float*)d_in[10];
  const float* b2   = (const float*)d_in[11];
  const float* W3   = (const float*)d_in[12];
  const float* b3   = (const float*)d_in[13];

  char* ws = (char*)d_ws;
  size_t off = 0;
  auto alloc = [&](size_t n){ void* p = ws + off; off += (n + 255) & ~(size_t)255; return p; };

  bf16* xbf   = (bf16*)alloc((size_t)B_*T_*D_*2);
  bf16* W1hb  = (bf16*)alloc((size_t)1024*512*2);
  bf16* W2b   = (bf16*)alloc((size_t)1024*1024*2);
  bf16* W3b   = (bf16*)alloc((size_t)512*1024*2);
  bf16* Woutb = (bf16*)alloc((size_t)128*512*2);
  bf16* Wcb2  = (bf16*)alloc((size_t)2048*1024*2);
  float* bcb2 = (float*)alloc((size_t)2048*4);
  float* w1t  = (float*)alloc((size_t)1024*4);
  bf16* wbuf  = (bf16*)alloc((size_t)B_*H_*2);
  bf16* z1buf = (bf16*)alloc((size_t)B_*1024*2);
  bf16* z2buf = (bf16*)alloc((size_t)B_*1024*2);
  unsigned* cnts = (unsigned*)alloc((size_t)16*128*4);

  auto conv = [&](const float* in, bf16* out, int rows, int kin, int kout){
    int n = rows*kout;
    conv_k<<<(n + 255)/256, 256, 0, stream>>>(in, out, rows, kin, kout);
  };
  conv(x, xbf, B_*T_, D_, D_);
  conv(W1, W1hb, 1024, 513, 512);   // col 512 handled via w1t rank-1 term
  conv(W2, W2b, 1024, 1024, 1024);
  conv(W3, W3b, 512, 1024, 1024);
  conv(Wout, Woutb, 128, 512, 512);
  w1t_k<<<4, 256, 0, stream>>>(W1, w1t);
  wc2_k<<<(2048*1024)/256, 256, 0, stream>>>(Wih, Whh, bih, bhh, Wcb2, bcb2);
  init_k<<<(B_*H_ + 255)/256, 256, 0, stream>>>(wbuf, cnts);

  (void)hipFuncSetAttribute((const void*)persist_k,
                            hipFuncAttributeMaxDynamicSharedMemorySize, 75008);
  persist_k<<<128, 256, 75008, stream>>>(
      W1hb, W2b, W3b, Woutb, Wcb2, xbf,
      b1, b2, b3, bout, bcb2, w1t, ts,
      wbuf, z1buf, z2buf, cnts, (float*)d_out);
}

// Round 7
// 3119.203 us; speedup vs baseline: 6.6533x; 1.0793x over previous
//
#include <hip/hip_runtime.h>
#include <hip/hip_bf16.h>
#include <stdint.h>

// RecognitionODEGRU R6 — 16 chains (32 rows) x 16 n-blocks = 256 blocks.
// vs R5 (n=8,128 blocks): weight stream per block halved (262KB/eval), W3
// slice LDS-resident (k-phase weights free), all CUs occupied. Slab staging,
// coherent 8B-atomic handoff, RK4-in-registers unchanged (proven paths).
// Per-block per-eval ingest: 160KB coherent + 198KB weights (was 685KB).
//
// Shapes: B=512, T=8, D=512, H=512, NSTEPS=4.
// d_out: outs[-1] (512,128) | h (512,512) | c=zeros (512,512), f32.

#define B_ 512
#define T_ 8
#define H_ 512
#define D_ 512

typedef short short8 __attribute__((ext_vector_type(8)));
typedef float f32x4 __attribute__((ext_vector_type(4)));
typedef __hip_bfloat16 bf16;
typedef unsigned long long u64;

__device__ __forceinline__ float sigm(float x){ return 1.f/(1.f+__expf(-x)); }

#define MFMA16(a,b,c) __builtin_amdgcn_mfma_f32_16x16x32_bf16((a),(b),(c),0,0,0)
#define ALD4(p)   __hip_atomic_load((p), __ATOMIC_RELAXED, __HIP_MEMORY_SCOPE_AGENT)
#define ALD8(p)   __hip_atomic_load((const u64*)(p), __ATOMIC_RELAXED, __HIP_MEMORY_SCOPE_AGENT)
#define AST8(p,v) __hip_atomic_store((u64*)(p),(v),__ATOMIC_RELAXED,__HIP_MEMORY_SCOPE_AGENT)

__device__ __forceinline__ void wait_ge(unsigned* c, unsigned tgt, int* dead){
  if (threadIdx.x == 0){
    if (!*dead){
      int it = 0;
      while (ALD4(c) < tgt){
        __builtin_amdgcn_s_sleep(1);
        if (++it > 50000000){ *dead = 1; break; }  // terminate visibly, no hang
      }
    }
  }
  __syncthreads();
}
__device__ __forceinline__ void publish(unsigned* c){
  __builtin_amdgcn_s_waitcnt(0);   // each wave drains its stores before barrier
  __syncthreads();
  if (threadIdx.x == 0)
    __hip_atomic_fetch_add(c, 1u, __ATOMIC_RELAXED, __HIP_MEMORY_SCOPE_AGENT);
}

// Coherent slab stage: CH 8B-chunks/thread, 2^SH chunks per row; loads batched.
template<int CH, int SH>
__device__ __forceinline__ void stageC(bf16* lds, int lstr, const bf16* g, int gstr){
  u64 tmp[CH];
#pragma unroll
  for (int j = 0; j < CH; ++j){
    int idx = j*256 + threadIdx.x;
    tmp[j] = ALD8(g + (size_t)(idx >> SH)*gstr + (size_t)(idx & ((1<<SH)-1))*4);
  }
#pragma unroll
  for (int j = 0; j < CH; ++j){
    int idx = j*256 + threadIdx.x;
    *(u64*)&lds[(idx >> SH)*lstr + (idx & ((1<<SH)-1))*4] = tmp[j];
  }
}
// Plain (L2-cached) slab stage: CH 16B-chunks/thread, 2^SH chunks per row.
template<int CH, int SH>
__device__ __forceinline__ void stageP(bf16* lds, int lstr, const bf16* g, size_t gstr){
#pragma unroll
  for (int j = 0; j < CH; ++j){
    int idx = j*256 + threadIdx.x;
    *(short8*)&lds[(idx >> SH)*lstr + (idx & ((1<<SH)-1))*8] =
        *(const short8*)(g + (size_t)(idx >> SH)*gstr + (size_t)(idx & ((1<<SH)-1))*8);
  }
}

// LDS: slab 32x1032 @0 (66048B) | W3s 32x1032 @66048 (66048B, persistent)
//      scr 32x72 @132096 (4608B) | t0s/dts/tcs @136704 | dead @137088
__global__ __launch_bounds__(256, 1) void persist_k(
    const bf16* __restrict__ W1hb, const bf16* __restrict__ W2b,
    const bf16* __restrict__ W3b,  const bf16* __restrict__ Woutb,
    const bf16* __restrict__ Wc3,  const bf16* __restrict__ xbf,
    const float* __restrict__ b1,  const float* __restrict__ b2,
    const float* __restrict__ b3,  const float* __restrict__ bout,
    const float* __restrict__ bcb3,const float* __restrict__ w1t,
    const float* __restrict__ ts,
    bf16* wbuf, bf16* z1buf, bf16* z2buf,
    unsigned* cnts, float* dout)
{
  extern __shared__ char smem[];
  bf16* slab = (bf16*)smem;
  bf16* W3s  = (bf16*)(smem + 66048);
  bf16* scr  = (bf16*)(smem + 132096);
  float* t0s = (float*)(smem + 136704);
  float* dts = t0s + 32;
  float* tcs = dts + 32;
  int* dead  = (int*)(smem + 137088);

  const int tid = threadIdx.x, lane = tid & 63, wv = tid >> 6;
  const int fr = lane & 15, quad = lane >> 4;
  const int nb = blockIdx.x & 15;
  const int mb = blockIdx.x >> 4;     // 16 chains
  const int gm0 = mb * 32;
  const int wm = wv & 1;              // row half (all phases)
  const int wn2 = wv >> 1;            // 32-col slice (z phases)
  const int wn = wv >> 1;             // 16-col half (k/gates/final-h)

  unsigned* cz1 = cnts + mb*128;
  unsigned* cz2 = cz1 + 32;
  unsigned* cw  = cz1 + 64;
  unsigned* cgt = cz1 + 96;

  // W3 slice -> LDS once (32 k-cols of this block, K=1024)
  stageP<16,7>(W3s, 1032, W3b + (size_t)(32*nb)*1024, 1024);
  if (tid < 32){
    float t0 = ts[(gm0 + tid)*T_];
    t0s[tid] = t0; tcs[tid] = t0; dts[tid] = 0.f;
  }
  if (tid == 0) *dead = 0;
  __syncthreads();

  // per-lane constants
  float b1v[2], b2v[2], w1tv[2];
#pragma unroll
  for (int t = 0; t < 2; ++t){
    int col = 64*nb + 32*wn2 + 16*t + fr;
    b1v[t] = b1[col]; b2v[t] = b2[col]; w1tv[t] = w1t[col];
  }
  const float b3v = b3[32*nb + 16*wn + fr];
  float bcv[4];
#pragma unroll
  for (int g = 0; g < 4; ++g) bcv[g] = bcb3[nb*128 + g*32 + 16*wn + fr];
  const float bov = bout[16*(nb & 7) + fr];

  // weight row pointers (plain L2-cached)
  const bf16* w1p0 = W1hb + (size_t)(64*nb + 32*wn2      + fr)*512  + quad*8;
  const bf16* w1p1 = W1hb + (size_t)(64*nb + 32*wn2 + 16 + fr)*512  + quad*8;
  const bf16* w2p0 = W2b  + (size_t)(64*nb + 32*wn2      + fr)*1024 + quad*8;
  const bf16* w2p1 = W2b  + (size_t)(64*nb + 32*wn2 + 16 + fr)*1024 + quad*8;
  const bf16* wop  = Woutb + (size_t)(16*(nb & 7) + fr)*512 + quad*8;
  const bf16* wcp[4];
#pragma unroll
  for (int g = 0; g < 4; ++g)
    wcp[g] = Wc3 + (size_t)(nb*128 + g*32 + 16*wn + fr)*1024 + quad*8;

  float hreg[4] = {0,0,0,0}, kacc[4] = {0,0,0,0};
  unsigned tz1 = 16, tz2 = 16, tw = 16, tg = 16;

  for (int s = 0; s < T_; ++s){
    for (int sub = 0; sub < 4; ++sub){
      for (int e = 1; e <= 4; ++e){
        // ===== z1 = swish(w @ W1^T + t*w1t + b1), M32 N64 K512 =====
        wait_ge(cw, tw, dead);
        stageC<16,7>(slab, 520, wbuf + (size_t)gm0*512, 512);
        __syncthreads();
        {
          f32x4 a0 = {0,0,0,0}, a1 = {0,0,0,0};
#pragma unroll 4
          for (int k = 0; k < 16; ++k){
            short8 x = *(const short8*)&slab[(wm*16 + fr)*520 + k*32 + quad*8];
            a0 = MFMA16(x, *(const short8*)(w1p0 + k*32), a0);
            a1 = MFMA16(x, *(const short8*)(w1p1 + k*32), a1);
          }
#pragma unroll
          for (int j = 0; j < 4; ++j){
            int r = wm*16 + quad*4 + j;
            float v0 = a0[j] + b1v[0] + tcs[r]*w1tv[0];
            float v1 = a1[j] + b1v[1] + tcs[r]*w1tv[1];
            scr[r*72 + 32*wn2      + fr] = __float2bfloat16(v0*sigm(v0));
            scr[r*72 + 32*wn2 + 16 + fr] = __float2bfloat16(v1*sigm(v1));
          }
          __syncthreads();
          {  // repack 32x64 -> coherent 16B/thread
            int r = tid >> 3, c = tid & 7;
            u64* dst = (u64*)(z1buf + (size_t)(gm0 + r)*1024 + 64*nb + c*8);
            const u64* src = (const u64*)&scr[r*72 + c*8];
            AST8(dst, src[0]); AST8(dst + 1, src[1]);
          }
          publish(cz1);
        }
        // ===== z2 = swish(z1 @ W2^T + b2), M32 N64 K1024 =====
        wait_ge(cz1, tz1, dead); tz1 += 16;
        stageC<32,8>(slab, 1032, z1buf + (size_t)gm0*1024, 1024);
        __syncthreads();
        {
          f32x4 a0 = {0,0,0,0}, a1 = {0,0,0,0};
#pragma unroll 4
          for (int k = 0; k < 32; ++k){
            short8 x = *(const short8*)&slab[(wm*16 + fr)*1032 + k*32 + quad*8];
            a0 = MFMA16(x, *(const short8*)(w2p0 + k*32), a0);
            a1 = MFMA16(x, *(const short8*)(w2p1 + k*32), a1);
          }
#pragma unroll
          for (int j = 0; j < 4; ++j){
            int r = wm*16 + quad*4 + j;
            float v0 = a0[j] + b2v[0], v1 = a1[j] + b2v[1];
            scr[r*72 + 32*wn2      + fr] = __float2bfloat16(v0*sigm(v0));
            scr[r*72 + 32*wn2 + 16 + fr] = __float2bfloat16(v1*sigm(v1));
          }
          __syncthreads();
          {
            int r = tid >> 3, c = tid & 7;
            u64* dst = (u64*)(z2buf + (size_t)(gm0 + r)*1024 + 64*nb + c*8);
            const u64* src = (const u64*)&scr[r*72 + c*8];
            AST8(dst, src[0]); AST8(dst + 1, src[1]);
          }
          publish(cz2);
        }
        // ===== k = z2 @ W3^T + b3 ; RK4 in registers, M32 N32 K1024 =====
        wait_ge(cz2, tz2, dead); tz2 += 16;
        stageC<32,8>(slab, 1032, z2buf + (size_t)gm0*1024, 1024);
        __syncthreads();
        {
          f32x4 ak = {0,0,0,0};
#pragma unroll 8
          for (int k = 0; k < 32; ++k){
            short8 x = *(const short8*)&slab[(wm*16 + fr)*1032 + k*32 + quad*8];
            short8 b = *(const short8*)&W3s[(wn*16 + fr)*1032 + k*32 + quad*8];
            ak = MFMA16(x, b, ak);
          }
#pragma unroll
          for (int j = 0; j < 4; ++j){
            int row = wm*16 + quad*4 + j;
            float v = ak[j] + b3v;
            float dtv = dts[row];
            float ka = (e == 1) ? v : kacc[j] + ((e == 4) ? 1.f : 2.f)*v;
            float wn_;
            if (e < 4){ kacc[j] = ka; wn_ = hreg[j] + ((e == 3) ? 1.f : 0.5f)*dtv*v; }
            else      { hreg[j] = hreg[j] + dtv*(1.f/6.f)*ka; wn_ = hreg[j]; }
            scr[row*72 + wn*16 + fr] = __float2bfloat16(wn_);
          }
          __syncthreads();
          if (tid < 128){  // repack 32x32
            int r = tid >> 2, c = tid & 3;
            u64* dst = (u64*)(wbuf + (size_t)(gm0 + r)*512 + 32*nb + c*8);
            const u64* src = (const u64*)&scr[r*72 + c*8];
            AST8(dst, src[0]); AST8(dst + 1, src[1]);
          }
          if (tid < 32){
            float ce = (e <= 2) ? ((float)sub + 0.5f) : ((float)sub + 1.f);
            tcs[tid] = t0s[tid] + dts[tid]*ce;
          }
          publish(cw); tw += 16;
        }
      }
    }
    // ===== gates: [w|x_s] @ Wc3^T (4 groups r|z|hn|in x 32 cols), K=1024 =====
    wait_ge(cw, tw, dead);
    stageC<16,7>(slab, 1032, wbuf + (size_t)gm0*512, 512);
    stageP<8,6>(slab + 512, 1032, xbf + ((size_t)gm0*T_ + s)*512, (size_t)T_*512);
    __syncthreads();
    publish(cgt);   // old w consumed (staged); safe to overwrite after all 16 publish
    {
      f32x4 ag[4] = {{0,0,0,0},{0,0,0,0},{0,0,0,0},{0,0,0,0}};
#pragma unroll 4
      for (int k = 0; k < 32; ++k){
        short8 x = *(const short8*)&slab[(wm*16 + fr)*1032 + k*32 + quad*8];
#pragma unroll
        for (int g = 0; g < 4; ++g)
          ag[g] = MFMA16(x, *(const short8*)(wcp[g] + k*32), ag[g]);
      }
      wait_ge(cgt, tg, dead); tg += 16;
#pragma unroll
      for (int j = 0; j < 4; ++j){
        int row = wm*16 + quad*4 + j;
        float r_ = sigm(ag[0][j] + bcv[0]);
        float z_ = sigm(ag[1][j] + bcv[1]);
        float hn = ag[2][j] + bcv[2];
        float in = ag[3][j] + bcv[3];
        float n_ = tanhf(in + r_*hn);
        hreg[j] = (1.f - z_)*n_ + z_*hreg[j];
        scr[row*72 + wn*16 + fr] = __float2bfloat16(hreg[j]);
      }
      __syncthreads();
      if (tid < 128){
        int r = tid >> 2, c = tid & 3;
        u64* dst = (u64*)(wbuf + (size_t)(gm0 + r)*512 + 32*nb + c*8);
        const u64* src = (const u64*)&scr[r*72 + c*8];
        AST8(dst, src[0]); AST8(dst + 1, src[1]);
      }
      if (tid < 32){
        float t0n = ts[(gm0 + tid)*T_ + s];
        float t1  = (s < T_-1) ? ts[(gm0 + tid)*T_ + s + 1] : t0n;
        t0s[tid] = t0n; tcs[tid] = t0n; dts[tid] = (t1 - t0n)*0.25f;
      }
      publish(cw); tw += 16;
    }
  }
  // ===== final: out = h @ Wout^T + bout ; h ; c = 0 =====
  wait_ge(cw, tw, dead);
  stageC<16,7>(slab, 520, wbuf + (size_t)gm0*512, 512);
  __syncthreads();
  if (nb < 8 && wv < 2){   // 8 n-blocks x 16 cols cover the 128 outs; wv = row half
    f32x4 ao = {0,0,0,0};
#pragma unroll 4
    for (int k = 0; k < 16; ++k){
      short8 x = *(const short8*)&slab[(wv*16 + fr)*520 + k*32 + quad*8];
      ao = MFMA16(x, *(const short8*)(wop + k*32), ao);
    }
#pragma unroll
    for (int j = 0; j < 4; ++j)
      dout[(size_t)(gm0 + wv*16 + quad*4 + j)*128 + 16*nb + fr] = ao[j] + bov;
  }
#pragma unroll
  for (int j = 0; j < 4; ++j){
    int row = gm0 + wm*16 + quad*4 + j, col = 32*nb + 16*wn + fr;
    dout[(size_t)B_*128 + (size_t)row*512 + col] = hreg[j];
    dout[(size_t)B_*128 + (size_t)B_*512 + (size_t)row*512 + col] = 0.f;
  }
}

// ---- prolog kernels ----
__global__ void conv_k(const float* __restrict__ in, bf16* __restrict__ out,
                       int rows, int kin, int kout)
{
  int idx = blockIdx.x*256 + threadIdx.x;
  if (idx >= rows*kout) return;
  int r = idx / kout, k = idx - r*kout;
  out[idx] = __float2bfloat16(k < kin ? in[(size_t)r*kin + k] : 0.f);
}

__global__ void w1t_k(const float* __restrict__ W1, float* __restrict__ w1t)
{
  int i = blockIdx.x*256 + threadIdx.x;
  if (i < 1024) w1t[i] = W1[(size_t)i*513 + 512];
}

// Wc3 row R = n16*128 + g*32 + c; hidden col hc = n16*32 + c.
// K: [0:512]=h-part, [512:1024]=x-part. g=0:r g=1:z g=2:hn=[Whh_n|0] g=3:in=[0|Wih_n].
__global__ void wc3_k(const float* __restrict__ Wih, const float* __restrict__ Whh,
                      const float* __restrict__ bih, const float* __restrict__ bhh,
                      bf16* __restrict__ Wc3, float* __restrict__ bcb3)
{
  int idx = blockIdx.x*256 + threadIdx.x;
  if (idx >= 2048*1024) return;
  int R = idx >> 10, k = idx & 1023;
  int n16 = R >> 7, g = (R >> 5) & 3, c = R & 31;
  int hc = n16*32 + c;
  float v;
  if      (g == 0) v = (k < 512) ? Whh[(size_t)hc*512 + k]        : Wih[(size_t)hc*512 + k - 512];
  else if (g == 1) v = (k < 512) ? Whh[(size_t)(512+hc)*512 + k]  : Wih[(size_t)(512+hc)*512 + k - 512];
  else if (g == 2) v = (k < 512) ? Whh[(size_t)(1024+hc)*512 + k] : 0.f;
  else             v = (k < 512) ? 0.f                             : Wih[(size_t)(1024+hc)*512 + k - 512];
  Wc3[idx] = __float2bfloat16(v);
  if (k == 0){
    if      (g == 0) bcb3[R] = bih[hc] + bhh[hc];
    else if (g == 1) bcb3[R] = bih[512 + hc] + bhh[512 + hc];
    else if (g == 2) bcb3[R] = bhh[1024 + hc];
    else             bcb3[R] = bih[1024 + hc];
  }
}

__global__ void init_k(bf16* __restrict__ wbuf, unsigned* __restrict__ cnts)
{
  int idx = blockIdx.x*256 + threadIdx.x;
  if (idx < B_*H_) wbuf[idx] = __float2bfloat16(0.f);
  if (idx < 16*128){
    int off = idx & 127;
    cnts[idx] = (off == 64) ? 16u : 0u;   // cw pre-armed (initial w=0 published)
  }
}

extern "C" void kernel_launch(void* const* d_in, const int* in_sizes, int n_in,
                              void* d_out, int out_size, void* d_ws, size_t ws_size,
                              hipStream_t stream)
{
  const float* x    = (const float*)d_in[0];
  const float* ts   = (const float*)d_in[1];
  const float* Wih  = (const float*)d_in[2];
  const float* Whh  = (const float*)d_in[3];
  const float* bih  = (const float*)d_in[4];
  const float* bhh  = (const float*)d_in[5];
  const float* Wout = (const float*)d_in[6];
  const float* bout = (const float*)d_in[7];
  const float* W1   = (const float*)d_in[8];
  const float* b1   = (const float*)d_in[9];
  const float* W2   = (const float*)d_in[10];
  const float* b2   = (const float*)d_in[11];
  const float* W3   = (const float*)d_in[12];
  const float* b3   = (const float*)d_in[13];

  char* ws = (char*)d_ws;
  size_t off = 0;
  auto alloc = [&](size_t n){ void* p = ws + off; off += (n + 255) & ~(size_t)255; return p; };

  bf16* xbf   = (bf16*)alloc((size_t)B_*T_*D_*2);
  bf16* W1hb  = (bf16*)alloc((size_t)1024*512*2);
  bf16* W2b   = (bf16*)alloc((size_t)1024*1024*2);
  bf16* W3b   = (bf16*)alloc((size_t)512*1024*2);
  bf16* Woutb = (bf16*)alloc((size_t)128*512*2);
  bf16* Wc3   = (bf16*)alloc((size_t)2048*1024*2);
  float* bcb3 = (float*)alloc((size_t)2048*4);
  float* w1t  = (float*)alloc((size_t)1024*4);
  bf16* wbuf  = (bf16*)alloc((size_t)B_*H_*2);
  bf16* z1buf = (bf16*)alloc((size_t)B_*1024*2);
  bf16* z2buf = (bf16*)alloc((size_t)B_*1024*2);
  unsigned* cnts = (unsigned*)alloc((size_t)16*128*4);

  auto conv = [&](const float* in, bf16* out, int rows, int kin, int kout){
    int n = rows*kout;
    conv_k<<<(n + 255)/256, 256, 0, stream>>>(in, out, rows, kin, kout);
  };
  conv(x, xbf, B_*T_, D_, D_);
  conv(W1, W1hb, 1024, 513, 512);   // col 512 handled via w1t rank-1 term
  conv(W2, W2b, 1024, 1024, 1024);
  conv(W3, W3b, 512, 1024, 1024);
  conv(Wout, Woutb, 128, 512, 512);
  w1t_k<<<4, 256, 0, stream>>>(W1, w1t);
  wc3_k<<<(2048*1024)/256, 256, 0, stream>>>(Wih, Whh, bih, bhh, Wc3, bcb3);
  init_k<<<(B_*H_ + 255)/256, 256, 0, stream>>>(wbuf, cnts);

  (void)hipFuncSetAttribute((const void*)persist_k,
                            hipFuncAttributeMaxDynamicSharedMemorySize, 137216);
  persist_k<<<256, 256, 137216, stream>>>(
      W1hb, W2b, W3b, Woutb, Wc3, xbf,
      b1, b2, b3, bout, bcb3, w1t, ts,
      wbuf, z1buf, z2buf, cnts, (float*)d_out);
}